// Round 5
// baseline (387.248 us; speedup 1.0000x reference)
//
#include <hip/hip_runtime.h>
#include <math.h>

#define BB 2
#define SS 2048
#define DD 768
#define HH 12
#define DHH 64
#define DFFN 3072
#define MTOK (BB*SS)   // 4096

typedef __attribute__((ext_vector_type(8))) __bf16 bf16x8;
typedef __attribute__((ext_vector_type(4))) float f32x4;
typedef __attribute__((ext_vector_type(16))) float f32x16;

__device__ __forceinline__ unsigned short f2bf(float f) {
    unsigned int b = __builtin_bit_cast(unsigned int, f);
    b += 0x7FFFu + ((b >> 16) & 1u);           // RNE
    return (unsigned short)(b >> 16);
}

__device__ __forceinline__ void gload_lds16(const void* g, void* l) {
    __builtin_amdgcn_global_load_lds((const __attribute__((address_space(1))) unsigned int*)g,
                                     (__attribute__((address_space(3))) unsigned int*)l,
                                     16, 0, 0);
}

// ---------------------------------------------------------------------------
// bf16 MFMA GEMM: C[M,N] = A[M,K](bf16) @ Bt[N,K](bf16)^T + bias
// 128x128 tile, BK=64, 4 waves. ldA/ldB = row strides; Klen = reduction len.
// bias may be nullptr. ACT=1 -> exact GELU. OBF=1 -> bf16 out, else fp32.
// ---------------------------------------------------------------------------
template <int ACT, int OBF>
__global__ __launch_bounds__(256) void gemm_mfma(const unsigned short* __restrict__ A,
                                                 const unsigned short* __restrict__ Bt,
                                                 const float* __restrict__ bias,
                                                 void* __restrict__ Cout,
                                                 int M, int N, int ldA, int ldB, int Klen) {
    __shared__ unsigned short As[128 * 64];
    __shared__ unsigned short Bs[128 * 64];
    const int tid = threadIdx.x;
    const int lane = tid & 63;
    const int w = tid >> 6;
    const int l15 = lane & 15, l4 = lane >> 4;
    const int m0 = blockIdx.x * 128;
    const int n0 = blockIdx.y * 128;
    const int wr = (w >> 1) * 64;
    const int wc = (w & 1) * 64;

    f32x4 acc[4][4] = {};

    int srow[4], scd[4];
#pragma unroll
    for (int i = 0; i < 4; ++i) {
        int s = w * 256 + i * 64 + lane;
        srow[i] = s >> 3;                          // row (0..127), 8 chunks/row
        scd[i] = (((s & 7) ^ (srow[i] & 7))) * 8;  // swizzled source chunk (elems)
    }

    for (int k0 = 0; k0 < Klen; k0 += 64) {
        __syncthreads();
#pragma unroll
        for (int i = 0; i < 4; ++i) {
            const unsigned short* gA = A + (size_t)(m0 + srow[i]) * ldA + k0 + scd[i];
            gload_lds16(gA, &As[(w * 256 + i * 64) * 8]);
        }
#pragma unroll
        for (int i = 0; i < 4; ++i) {
            const unsigned short* gB = Bt + (size_t)(n0 + srow[i]) * ldB + k0 + scd[i];
            gload_lds16(gB, &Bs[(w * 256 + i * 64) * 8]);
        }
        __syncthreads();
#pragma unroll
        for (int ks = 0; ks < 2; ++ks) {
            bf16x8 af[4], bfr[4];
#pragma unroll
            for (int m = 0; m < 4; ++m) {
                int r = wr + m * 16 + l15;
                int c = (ks * 4 + l4) ^ (r & 7);
                af[m] = *(const bf16x8*)&As[(r * 8 + c) * 8];
            }
#pragma unroll
            for (int n = 0; n < 4; ++n) {
                int r = wc + n * 16 + l15;
                int c = (ks * 4 + l4) ^ (r & 7);
                bfr[n] = *(const bf16x8*)&Bs[(r * 8 + c) * 8];
            }
#pragma unroll
            for (int m = 0; m < 4; ++m)
#pragma unroll
                for (int n = 0; n < 4; ++n)
                    acc[m][n] = __builtin_amdgcn_mfma_f32_16x16x32_bf16(af[m], bfr[n], acc[m][n], 0, 0, 0);
        }
    }

#pragma unroll
    for (int n = 0; n < 4; ++n) {
        int col = n0 + wc + n * 16 + l15;
        float bv = bias ? bias[col] : 0.0f;
#pragma unroll
        for (int m = 0; m < 4; ++m) {
#pragma unroll
            for (int r = 0; r < 4; ++r) {
                int row = m0 + wr + m * 16 + l4 * 4 + r;
                float v = acc[m][n][r] + bv;
                if (ACT) v = 0.5f * v * (1.0f + erff(v * 0.70710678118654752f));
                if (OBF) ((unsigned short*)Cout)[(size_t)row * N + col] = f2bf(v);
                else     ((float*)Cout)[(size_t)row * N + col] = v;
            }
        }
    }
}

// ---------------------------------------------------------------------------
// MFMA flash attention, swapped-QK^T in-register softmax (32x32x16 MFMA).
// Block = 128 q-rows of one (b,h); 4 waves x 32 q-rows. KVBLK=64.
// QKV: [4096][2304] bf16 (Q|K|V). Vt: [24][64][2048] bf16. Ctx: bf16.
// Per wave: S^T = K@Q^T (lane owns q=lane&31), softmax lane-local in
// exp2-domain, PV as O^T = V^T@P^T (q stays lane-local; P^T built via
// pack + shfl_xor(32), no LDS round-trip).
// ---------------------------------------------------------------------------
__global__ __launch_bounds__(256) void attn_mfma2(const unsigned short* __restrict__ QKV,
                                                  const unsigned short* __restrict__ Vt,
                                                  unsigned short* __restrict__ Ctx) {
    __shared__ unsigned short Ks[64 * 64];
    __shared__ unsigned short Vs[64 * 64];
    const int tid = threadIdx.x;
    const int lane = tid & 63;
    const int w = tid >> 6;
    const int l31 = lane & 31;
    const int hi = lane >> 5;              // half-wave index
    const int bh = blockIdx.y;
    const int b = bh / HH, h = bh % HH;
    const int q0 = blockIdx.x * 128 + w * 32;
    const float CLOG = 0.18033688011112042f;   // 0.125 * log2(e)

    // Q fragments: qf[ks] = Q[q0+l31][h*64 + ks*16 + hi*8 .. +8)
    bf16x8 qf[4];
    {
        const unsigned short* qp = QKV + (size_t)(b * SS + q0 + l31) * 2304 + h * 64 + hi * 8;
        qf[0] = *(const bf16x8*)qp;
        qf[1] = *(const bf16x8*)(qp + 16);
        qf[2] = *(const bf16x8*)(qp + 32);
        qf[3] = *(const bf16x8*)(qp + 48);
    }

    f32x16 oacc[2] = {};       // O^T: oacc[d][r] = O[q=l31][dh=32d+(r&3)+8*(r>>2)+4*hi]
    float m_run = -1e30f, l_run = 0.0f;

    // staging slots (512 chunks of 16B per 64x64 tile): wave w: slots w*128+i*64+lane
    int arow[2], acd[2];
#pragma unroll
    for (int i = 0; i < 2; ++i) {
        int s = w * 128 + i * 64 + lane;
        arow[i] = s >> 3;
        acd[i] = ((s & 7) ^ (arow[i] & 7)) * 8;
    }

    for (int kt = 0; kt < SS / 64; ++kt) {
        const int k0 = kt * 64;
        __syncthreads();
#pragma unroll
        for (int i = 0; i < 2; ++i) {
            const unsigned short* gK = QKV + (size_t)(b * SS + k0 + arow[i]) * 2304 + DD + h * 64 + acd[i];
            gload_lds16(gK, &Ks[(w * 128 + i * 64) * 8]);
        }
#pragma unroll
        for (int i = 0; i < 2; ++i) {
            const unsigned short* gV = Vt + (size_t)(bh * 64 + arow[i]) * SS + k0 + acd[i];
            gload_lds16(gV, &Vs[(w * 128 + i * 64) * 8]);
        }
        __syncthreads();

        // S^T tiles: st[t][r] = S[kv=32t+(r&3)+8*(r>>2)+4*hi][q=l31]
        f32x16 st[2] = {};
#pragma unroll
        for (int t = 0; t < 2; ++t) {
#pragma unroll
            for (int ks = 0; ks < 4; ++ks) {
                int row = 32 * t + l31;
                int ch = (2 * ks + hi) ^ (row & 7);
                bf16x8 kf = *(const bf16x8*)&Ks[(row * 8 + ch) * 8];
                st[t] = __builtin_amdgcn_mfma_f32_32x32x16_bf16(kf, qf[ks], st[t], 0, 0, 0);
            }
        }

        // row max over this lane's 32 values + partner's 32 (exp2 domain)
        float pmax = st[0][0];
#pragma unroll
        for (int r = 1; r < 16; ++r) pmax = fmaxf(pmax, st[0][r]);
#pragma unroll
        for (int r = 0; r < 16; ++r) pmax = fmaxf(pmax, st[1][r]);
        pmax = fmaxf(pmax, __shfl_xor(pmax, 32));
        pmax *= CLOG;
        const float mn = fmaxf(m_run, pmax);
        const float corr = exp2f(m_run - mn);

        // p = exp2(s*CLOG - mn); pack into bf16 words; accumulate row sum
        unsigned int Wn[2][4][2];
        float rs = 0.0f;
#pragma unroll
        for (int t = 0; t < 2; ++t) {
#pragma unroll
            for (int blk = 0; blk < 4; ++blk) {
                float pa = exp2f(fmaf(st[t][4 * blk + 0], CLOG, -mn));
                float pb = exp2f(fmaf(st[t][4 * blk + 1], CLOG, -mn));
                float pc = exp2f(fmaf(st[t][4 * blk + 2], CLOG, -mn));
                float pd = exp2f(fmaf(st[t][4 * blk + 3], CLOG, -mn));
                rs += (pa + pb) + (pc + pd);
                Wn[t][blk][0] = (unsigned int)f2bf(pa) | ((unsigned int)f2bf(pb) << 16);
                Wn[t][blk][1] = (unsigned int)f2bf(pc) | ((unsigned int)f2bf(pd) << 16);
            }
        }
        rs += __shfl_xor(rs, 32);
        l_run = l_run * corr + rs;
        m_run = mn;

        // rescale O
#pragma unroll
        for (int d = 0; d < 2; ++d)
#pragma unroll
            for (int r = 0; r < 16; ++r) oacc[d][r] *= corr;

        // partner's packed words
        unsigned int PW[2][4][2];
#pragma unroll
        for (int t = 0; t < 2; ++t)
#pragma unroll
            for (int blk = 0; blk < 4; ++blk)
#pragma unroll
                for (int u = 0; u < 2; ++u) PW[t][blk][u] = __shfl_xor(Wn[t][blk][u], 32);

        // PV: O^T += V^T @ P^T
        const bool h1 = (hi == 1);
#pragma unroll
        for (int t = 0; t < 2; ++t) {
#pragma unroll
            for (int ks2 = 0; ks2 < 2; ++ks2) {
                union { unsigned int u[4]; bf16x8 v; } pu;
                pu.u[0] = h1 ? PW[t][2 * ks2 + 1][0] : Wn[t][2 * ks2][0];
                pu.u[1] = h1 ? PW[t][2 * ks2 + 1][1] : Wn[t][2 * ks2][1];
                pu.u[2] = h1 ? Wn[t][2 * ks2 + 1][0] : PW[t][2 * ks2][0];
                pu.u[3] = h1 ? Wn[t][2 * ks2 + 1][1] : PW[t][2 * ks2][1];
#pragma unroll
                for (int d = 0; d < 2; ++d) {
                    int row = 32 * d + l31;
                    int ch = (4 * t + 2 * ks2 + hi) ^ (row & 7);
                    bf16x8 vf = *(const bf16x8*)&Vs[(row * 8 + ch) * 8];
                    oacc[d] = __builtin_amdgcn_mfma_f32_32x32x16_bf16(vf, pu.v, oacc[d], 0, 0, 0);
                }
            }
        }
    }

    // epilogue: O[q][dh] = oacc/l_run, q = l31 lane-local
    const float inv = 1.0f / l_run;
    unsigned short* cp = Ctx + (size_t)(b * SS + q0 + l31) * DD + h * 64;
#pragma unroll
    for (int d = 0; d < 2; ++d) {
#pragma unroll
        for (int blk = 0; blk < 4; ++blk) {
            unsigned long long pk =
                  (unsigned long long)f2bf(oacc[d][4 * blk + 0] * inv)
                | ((unsigned long long)f2bf(oacc[d][4 * blk + 1] * inv) << 16)
                | ((unsigned long long)f2bf(oacc[d][4 * blk + 2] * inv) << 32)
                | ((unsigned long long)f2bf(oacc[d][4 * blk + 3] * inv) << 48);
            *(unsigned long long*)(cp + 32 * d + 8 * blk + 4 * hi) = pk;
        }
    }
}

// ---------------------------------------------------------------------------
// V transpose: QKV V-block [s][dh] -> Vt [bh][dh][s]  (bf16)
// ---------------------------------------------------------------------------
__global__ __launch_bounds__(256) void v_transpose(const unsigned short* __restrict__ QKV,
                                                   unsigned short* __restrict__ Vt) {
    __shared__ unsigned short t[64][66];
    const int tid = threadIdx.x;
    const int bh = blockIdx.y, b = bh / HH, h = bh % HH;
    const int s0 = blockIdx.x * 64;
    const int c = tid & 63, r0 = tid >> 6;
#pragma unroll
    for (int i = 0; i < 16; ++i) {
        int r = i * 4 + r0;
        t[r][c] = QKV[(size_t)(b * SS + s0 + r) * 2304 + 1536 + h * 64 + c];
    }
    __syncthreads();
#pragma unroll
    for (int i = 0; i < 16; ++i) {
        int r = i * 4 + r0;   // dh
        Vt[((size_t)bh * 64 + r) * SS + s0 + c] = t[c][r];
    }
}

// ---------------------------------------------------------------------------
// Weight transpose+convert: W fp32 [K][N] -> Wt bf16 [rowoff+N][K]
// ---------------------------------------------------------------------------
__global__ __launch_bounds__(256) void wtrans(const float* __restrict__ W,
                                              unsigned short* __restrict__ Wt,
                                              int K, int N, int rowoff) {
    __shared__ float t[32][33];
    const int tid = threadIdx.x;
    const int k0 = blockIdx.x * 32, n0 = blockIdx.y * 32;
    const int c = tid & 31, r0 = tid >> 5;
#pragma unroll
    for (int i = 0; i < 4; ++i) {
        int r = i * 8 + r0;
        t[r][c] = W[(size_t)(k0 + r) * N + n0 + c];
    }
    __syncthreads();
#pragma unroll
    for (int i = 0; i < 4; ++i) {
        int r = i * 8 + r0;
        Wt[(size_t)(rowoff + n0 + r) * K + k0 + c] = f2bf(t[c][r]);
    }
}

__global__ __launch_bounds__(256) void f2b_vec(const float* __restrict__ in,
                                               unsigned short* __restrict__ out, int n4) {
    int i = blockIdx.x * 256 + threadIdx.x;
    if (i < n4) {
        float4 v = ((const float4*)in)[i];
        unsigned long long pk = (unsigned long long)f2bf(v.x)
                              | ((unsigned long long)f2bf(v.y) << 16)
                              | ((unsigned long long)f2bf(v.z) << 32)
                              | ((unsigned long long)f2bf(v.w) << 48);
        ((unsigned long long*)out)[i] = pk;
    }
}

__global__ __launch_bounds__(256) void bias_concat(const float* __restrict__ q,
                                                   const float* __restrict__ k,
                                                   const float* __restrict__ v,
                                                   float* __restrict__ o) {
    int i = blockIdx.x * 256 + threadIdx.x;
    if (i < DD) { o[i] = q[i]; o[DD + i] = k[i]; o[2 * DD + i] = v[i]; }
}

// ---------------------------------------------------------------------------
// out_f = LayerNorm(a + p1 + p2 + bias)*g + be ; WB=1 also writes bf16 copy
// (p1/p2 = split-K GEMM partials, bias = that GEMM's bias)
// ---------------------------------------------------------------------------
template <int WB>
__global__ __launch_bounds__(256) void add_ln3(const float* __restrict__ a,
                                               const float* __restrict__ p1,
                                               const float* __restrict__ p2,
                                               const float* __restrict__ bias,
                                               const float* __restrict__ g,
                                               const float* __restrict__ be,
                                               float* __restrict__ outf,
                                               unsigned short* __restrict__ outb) {
    const int row = blockIdx.x;
    const int tid = threadIdx.x;
    float x[3];
    float s = 0.0f, s2 = 0.0f;
#pragma unroll
    for (int i = 0; i < 3; ++i) {
        int c = tid + i * 256;
        size_t idx = (size_t)row * DD + c;
        float v = a[idx] + p1[idx] + p2[idx] + bias[c];
        x[i] = v; s += v; s2 += v * v;
    }
#pragma unroll
    for (int off = 32; off; off >>= 1) {
        s += __shfl_down(s, off);
        s2 += __shfl_down(s2, off);
    }
    __shared__ float ws[8];
    const int wid = tid >> 6, lane = tid & 63;
    if (lane == 0) { ws[wid] = s; ws[4 + wid] = s2; }
    __syncthreads();
    if (tid == 0) {
        ws[0] = ws[0] + ws[1] + ws[2] + ws[3];
        ws[4] = ws[4] + ws[5] + ws[6] + ws[7];
    }
    __syncthreads();
    const float mean = ws[0] * (1.0f / DD);
    const float var = ws[4] * (1.0f / DD) - mean * mean;
    const float inv = rsqrtf(var + 1e-5f);
#pragma unroll
    for (int i = 0; i < 3; ++i) {
        int c = tid + i * 256;
        float res = (x[i] - mean) * inv * g[c] + be[c];
        outf[(size_t)row * DD + c] = res;
        if (WB) outb[(size_t)row * DD + c] = f2bf(res);
    }
}

// ---------------------------------------------------------------------------
extern "C" void kernel_launch(void* const* d_in, const int* in_sizes, int n_in,
                              void* d_out, int out_size, void* d_ws, size_t ws_size,
                              hipStream_t stream) {
    const float* x   = (const float*)d_in[0];
    const float* Wq  = (const float*)d_in[1];
    const float* bq  = (const float*)d_in[2];
    const float* Wk  = (const float*)d_in[3];
    const float* bk  = (const float*)d_in[4];
    const float* Wv  = (const float*)d_in[5];
    const float* bv  = (const float*)d_in[6];
    const float* Wo  = (const float*)d_in[7];
    const float* bo  = (const float*)d_in[8];
    const float* W1  = (const float*)d_in[9];
    const float* b1  = (const float*)d_in[10];
    const float* W2  = (const float*)d_in[11];
    const float* b2  = (const float*)d_in[12];
    const float* g1  = (const float*)d_in[13];
    const float* be1 = (const float*)d_in[14];
    const float* g2  = (const float*)d_in[15];
    const float* be2 = (const float*)d_in[16];
    float* out = (float*)d_out;

    char* w8 = (char*)d_ws;
    unsigned short* QKV = (unsigned short*)w8;                      // 18874368 B
    unsigned short* Hff = (unsigned short*)w8;                      // overlays after LN1
    unsigned short* Vt  = (unsigned short*)(w8 + 18874368);         // 6291456
    unsigned short* Ctxb  = (unsigned short*)(w8 + 25165824);       // 6291456
    unsigned short* xb    = (unsigned short*)(w8 + 31457280);       // 6291456 (also X2b)
    unsigned short* Wqkvt = (unsigned short*)(w8 + 37748736);       // 3538944
    unsigned short* Wot   = (unsigned short*)(w8 + 41287680);       // 1179648
    unsigned short* W1t   = (unsigned short*)(w8 + 42467328);       // 4718592
    unsigned short* W2t   = (unsigned short*)(w8 + 47185920);       // 4718592
    float* bqkv = (float*)(w8 + 51904512);                          // 9216 (+pad)
    float* Pa   = (float*)(w8 + 51916800);                          // 12582912
    float* Pb   = (float*)(w8 + 64499712);                          // 12582912
    float* X2   = (float*)(w8 + 77082624);                          // 12582912

    dim3 blk(256);

    // prep: conversions / transposes
    f2b_vec<<<dim3(3072), blk, 0, stream>>>(x, xb, MTOK * DD / 4);
    wtrans<<<dim3(24, 24), blk, 0, stream>>>(Wq, Wqkvt, DD, DD, 0);
    wtrans<<<dim3(24, 24), blk, 0, stream>>>(Wk, Wqkvt, DD, DD, DD);
    wtrans<<<dim3(24, 24), blk, 0, stream>>>(Wv, Wqkvt, DD, DD, 2 * DD);
    wtrans<<<dim3(24, 24), blk, 0, stream>>>(Wo, Wot, DD, DD, 0);
    wtrans<<<dim3(24, 96), blk, 0, stream>>>(W1, W1t, DD, DFFN, 0);
    wtrans<<<dim3(96, 24), blk, 0, stream>>>(W2, W2t, DFFN, DD, 0);
    bias_concat<<<dim3(3), blk, 0, stream>>>(bq, bk, bv, bqkv);

    // fused QKV projection -> QKV bf16 [4096][2304]
    gemm_mfma<0, 1><<<dim3(32, 18), blk, 0, stream>>>(xb, Wqkvt, bqkv, QKV,
                                                      MTOK, 3 * DD, DD, DD, DD);
    // V transpose -> Vt [24][64][2048]
    v_transpose<<<dim3(32, 24), blk, 0, stream>>>(QKV, Vt);
    // attention -> Ctxb bf16
    attn_mfma2<<<dim3(SS / 128, BB * HH), blk, 0, stream>>>(QKV, Vt, Ctxb);
    // output projection, split-K=2 (partials fp32, no bias)
    gemm_mfma<0, 0><<<dim3(32, 6), blk, 0, stream>>>(Ctxb, Wot, nullptr, Pa,
                                                     MTOK, DD, DD, DD, 384);
    gemm_mfma<0, 0><<<dim3(32, 6), blk, 0, stream>>>(Ctxb + 384, Wot + 384, nullptr, Pb,
                                                     MTOK, DD, DD, DD, 384);
    // residual + Wo-partial-sum + bias + LN1 -> X2 fp32 + X2b bf16 (xb region)
    add_ln3<1><<<dim3(MTOK), blk, 0, stream>>>(x, Pa, Pb, bo, g1, be1, X2, xb);
    // FFN1 + GELU -> Hff bf16
    gemm_mfma<1, 1><<<dim3(32, 24), blk, 0, stream>>>(xb, W1t, b1, Hff,
                                                      MTOK, DFFN, DD, DD, DD);
    // FFN2, split-K=2 (K=3072 -> 2x1536)
    gemm_mfma<0, 0><<<dim3(32, 6), blk, 0, stream>>>(Hff, W2t, nullptr, Pa,
                                                     MTOK, DD, DFFN, DFFN, 1536);
    gemm_mfma<0, 0><<<dim3(32, 6), blk, 0, stream>>>(Hff + 1536, W2t + 1536, nullptr, Pb,
                                                     MTOK, DD, DFFN, DFFN, 1536);
    // residual + FFN2-partial-sum + bias + LN2 -> out
    add_ln3<0><<<dim3(MTOK), blk, 0, stream>>>(X2, Pa, Pb, b2, g2, be2, out, nullptr);
}

// Round 6
// 345.663 us; speedup vs baseline: 1.1203x; 1.1203x over previous
//
#include <hip/hip_runtime.h>
#include <math.h>

#define BB 2
#define SS 2048
#define DD 768
#define HH 12
#define DHH 64
#define DFFN 3072
#define MTOK (BB*SS)   // 4096

typedef __attribute__((ext_vector_type(8))) __bf16 bf16x8;
typedef __attribute__((ext_vector_type(4))) float f32x4;
typedef __attribute__((ext_vector_type(16))) float f32x16;

__device__ __forceinline__ unsigned short f2bf(float f) {
    unsigned int b = __builtin_bit_cast(unsigned int, f);
    b += 0x7FFFu + ((b >> 16) & 1u);           // RNE
    return (unsigned short)(b >> 16);
}

__device__ __forceinline__ void gload_lds16(const void* g, void* l) {
    __builtin_amdgcn_global_load_lds((const __attribute__((address_space(1))) unsigned int*)g,
                                     (__attribute__((address_space(3))) unsigned int*)l,
                                     16, 0, 0);
}

// ---------------------------------------------------------------------------
// bf16 MFMA GEMM: C[M,N] = A[M,K](bf16) @ Bt[N,K](bf16)^T + bias
// 128x128 tile, BK=64, 4 waves. Prefetch double-buffered LDS, ONE barrier
// per K-step (stage next -> compute cur -> sync). blockIdx.z = K-split index:
// A/B column offset z*Klen, fp32 out offset z*M*N (partials summed in add_ln3).
// ---------------------------------------------------------------------------
template <int ACT, int OBF>
__global__ __launch_bounds__(256) void gemm_mfma(const unsigned short* __restrict__ A,
                                                 const unsigned short* __restrict__ Bt,
                                                 const float* __restrict__ bias,
                                                 void* __restrict__ Cout,
                                                 int M, int N, int ldA, int ldB, int Klen) {
    __shared__ unsigned short As[2 * 128 * 64];
    __shared__ unsigned short Bs[2 * 128 * 64];
    const int tid = threadIdx.x;
    const int lane = tid & 63;
    const int w = tid >> 6;
    const int l15 = lane & 15, l4 = lane >> 4;
    const int m0 = blockIdx.x * 128;
    const int n0 = blockIdx.y * 128;
    const int z = blockIdx.z;
    const int wr = (w >> 1) * 64;
    const int wc = (w & 1) * 64;

    const unsigned short* Az = A + (size_t)z * Klen;
    const unsigned short* Bz = Bt + (size_t)z * Klen;

    f32x4 acc[4][4] = {};

    int srow[4], scd[4];
#pragma unroll
    for (int i = 0; i < 4; ++i) {
        int s = w * 256 + i * 64 + lane;
        srow[i] = s >> 3;                          // row (0..127), 8 chunks/row
        scd[i] = (((s & 7) ^ (srow[i] & 7))) * 8;  // swizzled source chunk (elems)
    }

    // prologue: stage tile 0 into buffer 0
#pragma unroll
    for (int i = 0; i < 4; ++i) {
        gload_lds16(Az + (size_t)(m0 + srow[i]) * ldA + scd[i], &As[(w * 256 + i * 64) * 8]);
        gload_lds16(Bz + (size_t)(n0 + srow[i]) * ldB + scd[i], &Bs[(w * 256 + i * 64) * 8]);
    }
    __syncthreads();

    int cb = 0;
    for (int k0 = 0; k0 < Klen; k0 += 64) {
        // stage next tile into other buffer (overlaps compute below)
        if (k0 + 64 < Klen) {
            const int nb = (cb ^ 1) * 128 * 64;
#pragma unroll
            for (int i = 0; i < 4; ++i) {
                gload_lds16(Az + (size_t)(m0 + srow[i]) * ldA + k0 + 64 + scd[i],
                            &As[nb + (w * 256 + i * 64) * 8]);
                gload_lds16(Bz + (size_t)(n0 + srow[i]) * ldB + k0 + 64 + scd[i],
                            &Bs[nb + (w * 256 + i * 64) * 8]);
            }
        }
        const unsigned short* Ac = &As[cb * 128 * 64];
        const unsigned short* Bc = &Bs[cb * 128 * 64];
#pragma unroll
        for (int ks = 0; ks < 2; ++ks) {
            bf16x8 af[4], bfr[4];
#pragma unroll
            for (int m = 0; m < 4; ++m) {
                int r = wr + m * 16 + l15;
                int c = (ks * 4 + l4) ^ (r & 7);
                af[m] = *(const bf16x8*)&Ac[(r * 8 + c) * 8];
            }
#pragma unroll
            for (int n = 0; n < 4; ++n) {
                int r = wc + n * 16 + l15;
                int c = (ks * 4 + l4) ^ (r & 7);
                bfr[n] = *(const bf16x8*)&Bc[(r * 8 + c) * 8];
            }
#pragma unroll
            for (int m = 0; m < 4; ++m)
#pragma unroll
                for (int n = 0; n < 4; ++n)
                    acc[m][n] = __builtin_amdgcn_mfma_f32_16x16x32_bf16(af[m], bfr[n], acc[m][n], 0, 0, 0);
        }
        __syncthreads();
        cb ^= 1;
    }

    const size_t zoff = (size_t)z * M * N;
#pragma unroll
    for (int n = 0; n < 4; ++n) {
        int col = n0 + wc + n * 16 + l15;
        float bv = bias ? bias[col] : 0.0f;
#pragma unroll
        for (int m = 0; m < 4; ++m) {
#pragma unroll
            for (int r = 0; r < 4; ++r) {
                int row = m0 + wr + m * 16 + l4 * 4 + r;
                float v = acc[m][n][r] + bv;
                if (ACT) v = 0.5f * v * (1.0f + erff(v * 0.70710678118654752f));
                if (OBF) ((unsigned short*)Cout)[(size_t)row * N + col] = f2bf(v);
                else     ((float*)Cout)[zoff + (size_t)row * N + col] = v;
            }
        }
    }
}

// ---------------------------------------------------------------------------
// MFMA flash attention, kv-split=2 (blockIdx.z), prefetch double-buffer.
// Block = 128 q-rows of one (b,h); 4 waves x 32 q-rows; z covers kv half.
// Outputs UNNORMALIZED O (fp32) + per-row (m,l) in exp2-domain; combined by
// attn_combine. Softmax lane-local (swapped QK^T), defer-max threshold 8.
// ---------------------------------------------------------------------------
__global__ __launch_bounds__(256) void attn_mfma3(const unsigned short* __restrict__ QKV,
                                                  const unsigned short* __restrict__ Vt,
                                                  float* __restrict__ Opart,   // [2][4096][768]
                                                  float* __restrict__ ML) {    // [2][24][2048][2]
    __shared__ unsigned short Ks[2 * 64 * 64];
    __shared__ unsigned short Vs[2 * 64 * 64];
    const int tid = threadIdx.x;
    const int lane = tid & 63;
    const int w = tid >> 6;
    const int l31 = lane & 31;
    const int hi = lane >> 5;
    const int bh = blockIdx.y;
    const int b = bh / HH, h = bh % HH;
    const int z = blockIdx.z;
    const int q0 = blockIdx.x * 128 + w * 32;
    const float CLOG = 0.18033688011112042f;   // 0.125 * log2(e)

    bf16x8 qf[4];
    {
        const unsigned short* qp = QKV + (size_t)(b * SS + q0 + l31) * 2304 + h * 64 + hi * 8;
        qf[0] = *(const bf16x8*)qp;
        qf[1] = *(const bf16x8*)(qp + 16);
        qf[2] = *(const bf16x8*)(qp + 32);
        qf[3] = *(const bf16x8*)(qp + 48);
    }

    f32x16 oacc[2] = {};
    float m_run = -1e30f, l_run = 0.0f;

    int arow[2], acd[2];
#pragma unroll
    for (int i = 0; i < 2; ++i) {
        int s = w * 128 + i * 64 + lane;
        arow[i] = s >> 3;
        acd[i] = ((s & 7) ^ (arow[i] & 7)) * 8;
    }

    const int kbase = z * (SS / 2);
    // prologue: stage tile 0 -> buffer 0
#pragma unroll
    for (int i = 0; i < 2; ++i) {
        gload_lds16(QKV + (size_t)(b * SS + kbase + arow[i]) * 2304 + DD + h * 64 + acd[i],
                    &Ks[(w * 128 + i * 64) * 8]);
        gload_lds16(Vt + (size_t)(bh * 64 + arow[i]) * SS + kbase + acd[i],
                    &Vs[(w * 128 + i * 64) * 8]);
    }
    __syncthreads();

    int cb = 0;
    for (int it = 0; it < SS / 128; ++it) {          // 16 tiles of 64 per z
        // stage next tile (overlaps compute)
        if (it + 1 < SS / 128) {
            const int k0n = kbase + (it + 1) * 64;
            const int nb = (cb ^ 1) * 64 * 64;
#pragma unroll
            for (int i = 0; i < 2; ++i) {
                gload_lds16(QKV + (size_t)(b * SS + k0n + arow[i]) * 2304 + DD + h * 64 + acd[i],
                            &Ks[nb + (w * 128 + i * 64) * 8]);
                gload_lds16(Vt + (size_t)(bh * 64 + arow[i]) * SS + k0n + acd[i],
                            &Vs[nb + (w * 128 + i * 64) * 8]);
            }
        }
        const unsigned short* Kc = &Ks[cb * 64 * 64];
        const unsigned short* Vc = &Vs[cb * 64 * 64];

        // S^T tiles: st[t][r] = S[kv=32t+(r&3)+8*(r>>2)+4*hi][q=l31]
        f32x16 st[2] = {};
#pragma unroll
        for (int t = 0; t < 2; ++t) {
#pragma unroll
            for (int ks = 0; ks < 4; ++ks) {
                int row = 32 * t + l31;
                int ch = (2 * ks + hi) ^ (row & 7);
                bf16x8 kf = *(const bf16x8*)&Kc[(row * 8 + ch) * 8];
                st[t] = __builtin_amdgcn_mfma_f32_32x32x16_bf16(kf, qf[ks], st[t], 0, 0, 0);
            }
        }

        // row max (exp2 domain)
        float pmax = st[0][0];
#pragma unroll
        for (int r = 1; r < 16; ++r) pmax = fmaxf(pmax, st[0][r]);
#pragma unroll
        for (int r = 0; r < 16; ++r) pmax = fmaxf(pmax, st[1][r]);
        pmax = fmaxf(pmax, __shfl_xor(pmax, 32));
        pmax *= CLOG;

        // defer-max: only rescale when some row grew by > 8
        if (!__all(pmax <= m_run + 8.0f)) {
            float mn = fmaxf(m_run, pmax);
            float corr = exp2f(m_run - mn);
#pragma unroll
            for (int d = 0; d < 2; ++d)
#pragma unroll
                for (int r = 0; r < 16; ++r) oacc[d][r] *= corr;
            l_run *= corr;
            m_run = mn;
        }

        // p = exp2(s*CLOG - m_run); pack bf16; row-sum
        unsigned int Wn[2][4][2];
        float rs = 0.0f;
#pragma unroll
        for (int t = 0; t < 2; ++t) {
#pragma unroll
            for (int blk = 0; blk < 4; ++blk) {
                float pa = exp2f(fmaf(st[t][4 * blk + 0], CLOG, -m_run));
                float pb = exp2f(fmaf(st[t][4 * blk + 1], CLOG, -m_run));
                float pc = exp2f(fmaf(st[t][4 * blk + 2], CLOG, -m_run));
                float pd = exp2f(fmaf(st[t][4 * blk + 3], CLOG, -m_run));
                rs += (pa + pb) + (pc + pd);
                Wn[t][blk][0] = (unsigned int)f2bf(pa) | ((unsigned int)f2bf(pb) << 16);
                Wn[t][blk][1] = (unsigned int)f2bf(pc) | ((unsigned int)f2bf(pd) << 16);
            }
        }
        rs += __shfl_xor(rs, 32);
        l_run += rs;

        // PV: O^T += V^T @ P^T.  Exchange only the words the partner needs
        // (8 shuffles/tile instead of 16).
#pragma unroll
        for (int t = 0; t < 2; ++t) {
#pragma unroll
            for (int ks2 = 0; ks2 < 2; ++ks2) {
                unsigned int ex0 = __shfl_xor(hi ? Wn[t][2 * ks2][0] : Wn[t][2 * ks2 + 1][0], 32);
                unsigned int ex1 = __shfl_xor(hi ? Wn[t][2 * ks2][1] : Wn[t][2 * ks2 + 1][1], 32);
                union { unsigned int u[4]; bf16x8 v; } pu;
                pu.u[0] = hi ? ex0 : Wn[t][2 * ks2][0];
                pu.u[1] = hi ? ex1 : Wn[t][2 * ks2][1];
                pu.u[2] = hi ? Wn[t][2 * ks2 + 1][0] : ex0;
                pu.u[3] = hi ? Wn[t][2 * ks2 + 1][1] : ex1;
#pragma unroll
                for (int d = 0; d < 2; ++d) {
                    int row = 32 * d + l31;
                    int ch = (4 * t + 2 * ks2 + hi) ^ (row & 7);
                    bf16x8 vf = *(const bf16x8*)&Vc[(row * 8 + ch) * 8];
                    oacc[d] = __builtin_amdgcn_mfma_f32_32x32x16_bf16(vf, pu.v, oacc[d], 0, 0, 0);
                }
            }
        }
        __syncthreads();
        cb ^= 1;
    }

    // epilogue: unnormalized O (fp32) + (m,l)
    float* op = Opart + (size_t)z * MTOK * DD + (size_t)(b * SS + q0 + l31) * DD + h * 64;
#pragma unroll
    for (int d = 0; d < 2; ++d) {
#pragma unroll
        for (int blk = 0; blk < 4; ++blk) {
            float4 v = make_float4(oacc[d][4 * blk + 0], oacc[d][4 * blk + 1],
                                   oacc[d][4 * blk + 2], oacc[d][4 * blk + 3]);
            *(float4*)(op + 32 * d + 8 * blk + 4 * hi) = v;
        }
    }
    if (hi == 0) {
        size_t mi = (((size_t)z * BB * HH + bh) * SS + (q0 + l31)) * 2;
        ML[mi] = m_run;
        ML[mi + 1] = l_run;
    }
}

// ---------------------------------------------------------------------------
// Combine the two kv-split partials -> Ctx bf16. One block per token row.
// ---------------------------------------------------------------------------
__global__ __launch_bounds__(256) void attn_combine(const float* __restrict__ Opart,
                                                    const float* __restrict__ ML,
                                                    unsigned short* __restrict__ Ctx) {
    const int row = blockIdx.x;
    const int tid = threadIdx.x;
    const int b = row >> 11, s = row & 2047;
    const float* r0 = Opart + (size_t)row * DD;
    const float* r1 = Opart + (size_t)MTOK * DD + (size_t)row * DD;
    unsigned short* co = Ctx + (size_t)row * DD;
#pragma unroll
    for (int i = 0; i < 3; ++i) {
        int c = tid + i * 256;
        int h = c >> 6;
        size_t i0 = (((size_t)(b * HH + h)) * SS + s) * 2;
        size_t i1 = (((size_t)(BB * HH + b * HH + h)) * SS + s) * 2;
        float m0 = ML[i0], l0 = ML[i0 + 1];
        float m1 = ML[i1], l1 = ML[i1 + 1];
        float M = fmaxf(m0, m1);
        float w0 = exp2f(m0 - M), w1 = exp2f(m1 - M);
        float inv = 1.0f / (w0 * l0 + w1 * l1);
        co[c] = f2bf((r0[c] * w0 + r1[c] * w1) * inv);
    }
}

// ---------------------------------------------------------------------------
__global__ __launch_bounds__(256) void v_transpose(const unsigned short* __restrict__ QKV,
                                                   unsigned short* __restrict__ Vt) {
    __shared__ unsigned short t[64][66];
    const int tid = threadIdx.x;
    const int bh = blockIdx.y, b = bh / HH, h = bh % HH;
    const int s0 = blockIdx.x * 64;
    const int c = tid & 63, r0 = tid >> 6;
#pragma unroll
    for (int i = 0; i < 16; ++i) {
        int r = i * 4 + r0;
        t[r][c] = QKV[(size_t)(b * SS + s0 + r) * 2304 + 1536 + h * 64 + c];
    }
    __syncthreads();
#pragma unroll
    for (int i = 0; i < 16; ++i) {
        int r = i * 4 + r0;   // dh
        Vt[((size_t)bh * 64 + r) * SS + s0 + c] = t[c][r];
    }
}

__global__ __launch_bounds__(256) void wtrans(const float* __restrict__ W,
                                              unsigned short* __restrict__ Wt,
                                              int K, int N, int rowoff) {
    __shared__ float t[32][33];
    const int tid = threadIdx.x;
    const int k0 = blockIdx.x * 32, n0 = blockIdx.y * 32;
    const int c = tid & 31, r0 = tid >> 5;
#pragma unroll
    for (int i = 0; i < 4; ++i) {
        int r = i * 8 + r0;
        t[r][c] = W[(size_t)(k0 + r) * N + n0 + c];
    }
    __syncthreads();
#pragma unroll
    for (int i = 0; i < 4; ++i) {
        int r = i * 8 + r0;
        Wt[(size_t)(rowoff + n0 + r) * K + k0 + c] = f2bf(t[c][r]);
    }
}

__global__ __launch_bounds__(256) void f2b_vec(const float* __restrict__ in,
                                               unsigned short* __restrict__ out, int n4) {
    int i = blockIdx.x * 256 + threadIdx.x;
    if (i < n4) {
        float4 v = ((const float4*)in)[i];
        unsigned long long pk = (unsigned long long)f2bf(v.x)
                              | ((unsigned long long)f2bf(v.y) << 16)
                              | ((unsigned long long)f2bf(v.z) << 32)
                              | ((unsigned long long)f2bf(v.w) << 48);
        ((unsigned long long*)out)[i] = pk;
    }
}

__global__ __launch_bounds__(256) void bias_concat(const float* __restrict__ q,
                                                   const float* __restrict__ k,
                                                   const float* __restrict__ v,
                                                   float* __restrict__ o) {
    int i = blockIdx.x * 256 + threadIdx.x;
    if (i < DD) { o[i] = q[i]; o[DD + i] = k[i]; o[2 * DD + i] = v[i]; }
}

// ---------------------------------------------------------------------------
// out_f = LayerNorm(a + p1 + p2 + bias)*g + be ; WB=1 also writes bf16 copy
// ---------------------------------------------------------------------------
template <int WB>
__global__ __launch_bounds__(256) void add_ln3(const float* __restrict__ a,
                                               const float* __restrict__ p1,
                                               const float* __restrict__ p2,
                                               const float* __restrict__ bias,
                                               const float* __restrict__ g,
                                               const float* __restrict__ be,
                                               float* __restrict__ outf,
                                               unsigned short* __restrict__ outb) {
    const int row = blockIdx.x;
    const int tid = threadIdx.x;
    float x[3];
    float s = 0.0f, s2 = 0.0f;
#pragma unroll
    for (int i = 0; i < 3; ++i) {
        int c = tid + i * 256;
        size_t idx = (size_t)row * DD + c;
        float v = a[idx] + p1[idx] + p2[idx] + bias[c];
        x[i] = v; s += v; s2 += v * v;
    }
#pragma unroll
    for (int off = 32; off; off >>= 1) {
        s += __shfl_down(s, off);
        s2 += __shfl_down(s2, off);
    }
    __shared__ float ws[8];
    const int wid = tid >> 6, lane = tid & 63;
    if (lane == 0) { ws[wid] = s; ws[4 + wid] = s2; }
    __syncthreads();
    if (tid == 0) {
        ws[0] = ws[0] + ws[1] + ws[2] + ws[3];
        ws[4] = ws[4] + ws[5] + ws[6] + ws[7];
    }
    __syncthreads();
    const float mean = ws[0] * (1.0f / DD);
    const float var = ws[4] * (1.0f / DD) - mean * mean;
    const float inv = rsqrtf(var + 1e-5f);
#pragma unroll
    for (int i = 0; i < 3; ++i) {
        int c = tid + i * 256;
        float res = (x[i] - mean) * inv * g[c] + be[c];
        outf[(size_t)row * DD + c] = res;
        if (WB) outb[(size_t)row * DD + c] = f2bf(res);
    }
}

// ---------------------------------------------------------------------------
extern "C" void kernel_launch(void* const* d_in, const int* in_sizes, int n_in,
                              void* d_out, int out_size, void* d_ws, size_t ws_size,
                              hipStream_t stream) {
    const float* x   = (const float*)d_in[0];
    const float* Wq  = (const float*)d_in[1];
    const float* bq  = (const float*)d_in[2];
    const float* Wk  = (const float*)d_in[3];
    const float* bk  = (const float*)d_in[4];
    const float* Wv  = (const float*)d_in[5];
    const float* bv  = (const float*)d_in[6];
    const float* Wo  = (const float*)d_in[7];
    const float* bo  = (const float*)d_in[8];
    const float* W1  = (const float*)d_in[9];
    const float* b1  = (const float*)d_in[10];
    const float* W2  = (const float*)d_in[11];
    const float* b2  = (const float*)d_in[12];
    const float* g1  = (const float*)d_in[13];
    const float* be1 = (const float*)d_in[14];
    const float* g2  = (const float*)d_in[15];
    const float* be2 = (const float*)d_in[16];
    float* out = (float*)d_out;

    char* w8 = (char*)d_ws;
    unsigned short* QKV = (unsigned short*)w8;                      // 18874368 B
    unsigned short* Hff = (unsigned short*)w8;                      // overlays after LN1
    unsigned short* Vt  = (unsigned short*)(w8 + 18874368);         // 6291456
    unsigned short* Ctxb  = (unsigned short*)(w8 + 25165824);       // 6291456
    unsigned short* xb    = (unsigned short*)(w8 + 31457280);       // 6291456 (also X2b)
    unsigned short* Wqkvt = (unsigned short*)(w8 + 37748736);       // 3538944
    unsigned short* Wot   = (unsigned short*)(w8 + 41287680);       // 1179648
    unsigned short* W1t   = (unsigned short*)(w8 + 42467328);       // 4718592
    unsigned short* W2t   = (unsigned short*)(w8 + 47185920);       // 4718592
    float* bqkv = (float*)(w8 + 51904512);                          // 9216 (+pad)
    float* Pa   = (float*)(w8 + 51916800);                          // 12582912 (also O-partial z=0)
    float* Pb   = (float*)(w8 + 64499712);                          // 12582912 (also O-partial z=1)
    float* X2   = (float*)(w8 + 77082624);                          // 12582912
    float* ML   = (float*)(w8 + 89665536);                          // 786432

    dim3 blk(256);

    // prep: conversions / transposes
    f2b_vec<<<dim3(3072), blk, 0, stream>>>(x, xb, MTOK * DD / 4);
    wtrans<<<dim3(24, 24), blk, 0, stream>>>(Wq, Wqkvt, DD, DD, 0);
    wtrans<<<dim3(24, 24), blk, 0, stream>>>(Wk, Wqkvt, DD, DD, DD);
    wtrans<<<dim3(24, 24), blk, 0, stream>>>(Wv, Wqkvt, DD, DD, 2 * DD);
    wtrans<<<dim3(24, 24), blk, 0, stream>>>(Wo, Wot, DD, DD, 0);
    wtrans<<<dim3(24, 96), blk, 0, stream>>>(W1, W1t, DD, DFFN, 0);
    wtrans<<<dim3(96, 24), blk, 0, stream>>>(W2, W2t, DFFN, DD, 0);
    bias_concat<<<dim3(3), blk, 0, stream>>>(bq, bk, bv, bqkv);

    // fused QKV projection -> QKV bf16 [4096][2304]
    gemm_mfma<0, 1><<<dim3(32, 18, 1), blk, 0, stream>>>(xb, Wqkvt, bqkv, QKV,
                                                         MTOK, 3 * DD, DD, DD, DD);
    // V transpose -> Vt [24][64][2048]
    v_transpose<<<dim3(32, 24), blk, 0, stream>>>(QKV, Vt);
    // attention, kv-split=2 -> Pa/Pb (unnormalized fp32) + ML
    attn_mfma3<<<dim3(SS / 128, BB * HH, 2), blk, 0, stream>>>(QKV, Vt, Pa, ML);
    // combine -> Ctxb bf16
    attn_combine<<<dim3(MTOK), blk, 0, stream>>>(Pa, ML, Ctxb);
    // output projection, split-K=2 in ONE launch -> Pa/Pb
    gemm_mfma<0, 0><<<dim3(32, 6, 2), blk, 0, stream>>>(Ctxb, Wot, nullptr, Pa,
                                                        MTOK, DD, DD, DD, 384);
    // residual + Wo-partials + bias + LN1 -> X2 fp32 + X2b bf16 (xb region)
    add_ln3<1><<<dim3(MTOK), blk, 0, stream>>>(x, Pa, Pb, bo, g1, be1, X2, xb);
    // FFN1 + GELU -> Hff bf16
    gemm_mfma<1, 1><<<dim3(32, 24, 1), blk, 0, stream>>>(xb, W1t, b1, Hff,
                                                         MTOK, DFFN, DD, DD, DD);
    // FFN2, split-K=2 in ONE launch -> Pa/Pb
    gemm_mfma<0, 0><<<dim3(32, 6, 2), blk, 0, stream>>>(Hff, W2t, nullptr, Pa,
                                                        MTOK, DD, DFFN, DFFN, 1536);
    // residual + FFN2-partials + bias + LN2 -> out
    add_ln3<0><<<dim3(MTOK), blk, 0, stream>>>(X2, Pa, Pb, b2, g2, be2, out, nullptr);
}

// Round 10
// 345.166 us; speedup vs baseline: 1.1219x; 1.0014x over previous
//
#include <hip/hip_runtime.h>
#include <math.h>

#define BB 2
#define SS 2048
#define DD 768
#define HH 12
#define DHH 64
#define DFFN 3072
#define MTOK (BB*SS)   // 4096
#define KVSPL 4

typedef __attribute__((ext_vector_type(8))) __bf16 bf16x8;
typedef __attribute__((ext_vector_type(4))) float f32x4;
typedef __attribute__((ext_vector_type(16))) float f32x16;

__device__ __forceinline__ unsigned short f2bf(float f) {
    unsigned int b = __builtin_bit_cast(unsigned int, f);
    b += 0x7FFFu + ((b >> 16) & 1u);           // RNE
    return (unsigned short)(b >> 16);
}
__device__ __forceinline__ float bf2f(unsigned short u) {
    unsigned int b = ((unsigned int)u) << 16;
    return __builtin_bit_cast(float, b);
}

__device__ __forceinline__ void gload_lds16(const void* g, void* l) {
    __builtin_amdgcn_global_load_lds((const __attribute__((address_space(1))) unsigned int*)g,
                                     (__attribute__((address_space(3))) unsigned int*)l,
                                     16, 0, 0);
}

// ---------------------------------------------------------------------------
// Cross-half (lane i <-> i+32) exchange. Preferred: v_permlane32_swap_b32
// (VALU pipe, no LDS traffic). Fallback: __shfl_xor via ds_bpermute.
// pswap(X,Y): r0 = {X.lo_half, Y.lo_half}, r1 = {X.hi_half, Y.hi_half}
// (half = lane<32 / lane>=32), elementwise per lane pair (l, l+32).
// ---------------------------------------------------------------------------
#if __has_builtin(__builtin_amdgcn_permlane32_swap)
#define HAVE_PSWAP 1
__device__ __forceinline__ void pswap(unsigned int x, unsigned int y,
                                      unsigned int& r0, unsigned int& r1) {
    auto r = __builtin_amdgcn_permlane32_swap(x, y, false, false);
    r0 = r[0]; r1 = r[1];
}
#else
#define HAVE_PSWAP 0
__device__ __forceinline__ void pswap(unsigned int x, unsigned int y,
                                      unsigned int& r0, unsigned int& r1) {
    // emulate: r0 = lo-half ? x : shfl(y), r1 = lo-half ? shfl(x) : y
    unsigned int xs = __shfl_xor(x, 32);
    unsigned int ys = __shfl_xor(y, 32);
    bool hi = (threadIdx.x & 32) != 0;
    r0 = hi ? ys : x;
    r1 = hi ? y : xs;
}
#endif

__device__ __forceinline__ float xhalf_max(float v) {
    unsigned int u = __builtin_bit_cast(unsigned int, v);
    unsigned int a, b;
    pswap(u, u, a, b);
    return fmaxf(__builtin_bit_cast(float, a), __builtin_bit_cast(float, b));
}
__device__ __forceinline__ float xhalf_sum(float v) {
    unsigned int u = __builtin_bit_cast(unsigned int, v);
    unsigned int a, b;
    pswap(u, u, a, b);
    return __builtin_bit_cast(float, a) + __builtin_bit_cast(float, b);
}

// ---------------------------------------------------------------------------
// bf16 MFMA GEMM: C[M,N] = A[M,K](bf16) @ Bt[N,K](bf16)^T + bias
// 128x128 tile, BK=64, 4 waves. Prefetch double-buffered LDS, ONE barrier
// per K-step. blockIdx.z = K-split index (fp32 out offset z*M*N).
// ---------------------------------------------------------------------------
template <int ACT, int OBF>
__global__ __launch_bounds__(256) void gemm_mfma(const unsigned short* __restrict__ A,
                                                 const unsigned short* __restrict__ Bt,
                                                 const float* __restrict__ bias,
                                                 void* __restrict__ Cout,
                                                 int M, int N, int ldA, int ldB, int Klen) {
    __shared__ unsigned short As[2 * 128 * 64];
    __shared__ unsigned short Bs[2 * 128 * 64];
    const int tid = threadIdx.x;
    const int lane = tid & 63;
    const int w = tid >> 6;
    const int l15 = lane & 15, l4 = lane >> 4;
    const int m0 = blockIdx.x * 128;
    const int n0 = blockIdx.y * 128;
    const int z = blockIdx.z;
    const int wr = (w >> 1) * 64;
    const int wc = (w & 1) * 64;

    const unsigned short* Az = A + (size_t)z * Klen;
    const unsigned short* Bz = Bt + (size_t)z * Klen;

    f32x4 acc[4][4] = {};

    int srow[4], scd[4];
#pragma unroll
    for (int i = 0; i < 4; ++i) {
        int s = w * 256 + i * 64 + lane;
        srow[i] = s >> 3;
        scd[i] = (((s & 7) ^ (srow[i] & 7))) * 8;
    }

#pragma unroll
    for (int i = 0; i < 4; ++i) {
        gload_lds16(Az + (size_t)(m0 + srow[i]) * ldA + scd[i], &As[(w * 256 + i * 64) * 8]);
        gload_lds16(Bz + (size_t)(n0 + srow[i]) * ldB + scd[i], &Bs[(w * 256 + i * 64) * 8]);
    }
    __syncthreads();

    int cb = 0;
    for (int k0 = 0; k0 < Klen; k0 += 64) {
        if (k0 + 64 < Klen) {
            const int nb = (cb ^ 1) * 128 * 64;
#pragma unroll
            for (int i = 0; i < 4; ++i) {
                gload_lds16(Az + (size_t)(m0 + srow[i]) * ldA + k0 + 64 + scd[i],
                            &As[nb + (w * 256 + i * 64) * 8]);
                gload_lds16(Bz + (size_t)(n0 + srow[i]) * ldB + k0 + 64 + scd[i],
                            &Bs[nb + (w * 256 + i * 64) * 8]);
            }
        }
        const unsigned short* Ac = &As[cb * 128 * 64];
        const unsigned short* Bc = &Bs[cb * 128 * 64];
#pragma unroll
        for (int ks = 0; ks < 2; ++ks) {
            bf16x8 af[4], bfr[4];
#pragma unroll
            for (int m = 0; m < 4; ++m) {
                int r = wr + m * 16 + l15;
                int c = (ks * 4 + l4) ^ (r & 7);
                af[m] = *(const bf16x8*)&Ac[(r * 8 + c) * 8];
            }
#pragma unroll
            for (int n = 0; n < 4; ++n) {
                int r = wc + n * 16 + l15;
                int c = (ks * 4 + l4) ^ (r & 7);
                bfr[n] = *(const bf16x8*)&Bc[(r * 8 + c) * 8];
            }
#pragma unroll
            for (int m = 0; m < 4; ++m)
#pragma unroll
                for (int n = 0; n < 4; ++n)
                    acc[m][n] = __builtin_amdgcn_mfma_f32_16x16x32_bf16(af[m], bfr[n], acc[m][n], 0, 0, 0);
        }
        __syncthreads();
        cb ^= 1;
    }

    const size_t zoff = (size_t)z * M * N;
#pragma unroll
    for (int n = 0; n < 4; ++n) {
        int col = n0 + wc + n * 16 + l15;
        float bv = bias ? bias[col] : 0.0f;
#pragma unroll
        for (int m = 0; m < 4; ++m) {
#pragma unroll
            for (int r = 0; r < 4; ++r) {
                int row = m0 + wr + m * 16 + l4 * 4 + r;
                float v = acc[m][n][r] + bv;
                if (ACT) v = 0.5f * v * (1.0f + erff(v * 0.70710678118654752f));
                if (OBF) ((unsigned short*)Cout)[(size_t)row * N + col] = f2bf(v);
                else     ((float*)Cout)[zoff + (size_t)row * N + col] = v;
            }
        }
    }
}

// ---------------------------------------------------------------------------
// MFMA flash attention, kv-split=KVSPL (blockIdx.z), prefetch double-buffer.
// Block = 128 q-rows of one (b,h); 4 waves x 32 q-rows; z covers SS/KVSPL kv.
// Outputs UNNORMALIZED O (bf16) + per-row (m,l) exp2-domain -> attn_combine.
// Cross-half exchange via pswap (permlane32_swap or shfl fallback).
// ---------------------------------------------------------------------------
__global__ __launch_bounds__(256) void attn_mfma4(const unsigned short* __restrict__ QKV,
                                                  const unsigned short* __restrict__ Vt,
                                                  unsigned short* __restrict__ Opart, // [KVSPL][4096][768]
                                                  float* __restrict__ ML) {           // [KVSPL][24][2048][2]
    __shared__ unsigned short Ks[2 * 64 * 64];
    __shared__ unsigned short Vs[2 * 64 * 64];
    const int tid = threadIdx.x;
    const int lane = tid & 63;
    const int w = tid >> 6;
    const int l31 = lane & 31;
    const int hi = lane >> 5;
    const int bh = blockIdx.y;
    const int b = bh / HH, h = bh % HH;
    const int z = blockIdx.z;
    const int q0 = blockIdx.x * 128 + w * 32;
    const float CLOG = 0.18033688011112042f;   // 0.125 * log2(e)

    bf16x8 qf[4];
    {
        const unsigned short* qp = QKV + (size_t)(b * SS + q0 + l31) * 2304 + h * 64 + hi * 8;
        qf[0] = *(const bf16x8*)qp;
        qf[1] = *(const bf16x8*)(qp + 16);
        qf[2] = *(const bf16x8*)(qp + 32);
        qf[3] = *(const bf16x8*)(qp + 48);
    }

    f32x16 oacc[2] = {};
    float m_run = -1e30f, l_run = 0.0f;

    int arow[2], acd[2];
#pragma unroll
    for (int i = 0; i < 2; ++i) {
        int s = w * 128 + i * 64 + lane;
        arow[i] = s >> 3;
        acd[i] = ((s & 7) ^ (arow[i] & 7)) * 8;
    }

    const int kbase = z * (SS / KVSPL);
#pragma unroll
    for (int i = 0; i < 2; ++i) {
        gload_lds16(QKV + (size_t)(b * SS + kbase + arow[i]) * 2304 + DD + h * 64 + acd[i],
                    &Ks[(w * 128 + i * 64) * 8]);
        gload_lds16(Vt + (size_t)(bh * 64 + arow[i]) * SS + kbase + acd[i],
                    &Vs[(w * 128 + i * 64) * 8]);
    }
    __syncthreads();

    int cb = 0;
    const int NT = (SS / KVSPL) / 64;
    for (int it = 0; it < NT; ++it) {
        if (it + 1 < NT) {
            const int k0n = kbase + (it + 1) * 64;
            const int nb = (cb ^ 1) * 64 * 64;
#pragma unroll
            for (int i = 0; i < 2; ++i) {
                gload_lds16(QKV + (size_t)(b * SS + k0n + arow[i]) * 2304 + DD + h * 64 + acd[i],
                            &Ks[nb + (w * 128 + i * 64) * 8]);
                gload_lds16(Vt + (size_t)(bh * 64 + arow[i]) * SS + k0n + acd[i],
                            &Vs[nb + (w * 128 + i * 64) * 8]);
            }
        }
        const unsigned short* Kc = &Ks[cb * 64 * 64];
        const unsigned short* Vc = &Vs[cb * 64 * 64];

        // S^T tiles: st[t][r] = S[kv=32t+(r&3)+8*(r>>2)+4*hi][q=l31]
        f32x16 st[2] = {};
#pragma unroll
        for (int t = 0; t < 2; ++t) {
#pragma unroll
            for (int ks = 0; ks < 4; ++ks) {
                int row = 32 * t + l31;
                int ch = (2 * ks + hi) ^ (row & 7);
                bf16x8 kf = *(const bf16x8*)&Kc[(row * 8 + ch) * 8];
                st[t] = __builtin_amdgcn_mfma_f32_32x32x16_bf16(kf, qf[ks], st[t], 0, 0, 0);
            }
        }

        // row max (exp2 domain), cross-half via pswap
        float pmax = st[0][0];
#pragma unroll
        for (int r = 1; r < 16; ++r) pmax = fmaxf(pmax, st[0][r]);
#pragma unroll
        for (int r = 0; r < 16; ++r) pmax = fmaxf(pmax, st[1][r]);
        pmax = xhalf_max(pmax) * CLOG;

        // defer-max: rescale only when some row grew by > 8
        if (!__all(pmax <= m_run + 8.0f)) {
            float mn = fmaxf(m_run, pmax);
            float corr = exp2f(m_run - mn);
#pragma unroll
            for (int d = 0; d < 2; ++d)
#pragma unroll
                for (int r = 0; r < 16; ++r) oacc[d][r] *= corr;
            l_run *= corr;
            m_run = mn;
        }

        // p = exp2(s*CLOG - m_run); pack bf16; row-sum
        unsigned int Wn[2][4][2];
        float rs = 0.0f;
#pragma unroll
        for (int t = 0; t < 2; ++t) {
#pragma unroll
            for (int blk = 0; blk < 4; ++blk) {
                float pa = exp2f(fmaf(st[t][4 * blk + 0], CLOG, -m_run));
                float pb = exp2f(fmaf(st[t][4 * blk + 1], CLOG, -m_run));
                float pc = exp2f(fmaf(st[t][4 * blk + 2], CLOG, -m_run));
                float pd = exp2f(fmaf(st[t][4 * blk + 3], CLOG, -m_run));
                rs += (pa + pb) + (pc + pd);
                Wn[t][blk][0] = (unsigned int)f2bf(pa) | ((unsigned int)f2bf(pb) << 16);
                Wn[t][blk][1] = (unsigned int)f2bf(pc) | ((unsigned int)f2bf(pd) << 16);
            }
        }
        l_run += xhalf_sum(rs);

        // PV: O^T += V^T @ P^T. P^T B-fragment via pswap:
        // pswap(X,Y) -> r0 = {X.lo,Y.lo} = u[0..1]'s source, r1 = {X.hi,Y.hi}
#pragma unroll
        for (int t = 0; t < 2; ++t) {
#pragma unroll
            for (int ks2 = 0; ks2 < 2; ++ks2) {
                unsigned int a0, a1, b0, b1;
                pswap(Wn[t][2 * ks2][0], Wn[t][2 * ks2 + 1][0], a0, a1);
                pswap(Wn[t][2 * ks2][1], Wn[t][2 * ks2 + 1][1], b0, b1);
                union { unsigned int u[4]; bf16x8 v; } pu;
                pu.u[0] = a0; pu.u[1] = b0;
                pu.u[2] = a1; pu.u[3] = b1;
#pragma unroll
                for (int d = 0; d < 2; ++d) {
                    int row = 32 * d + l31;
                    int ch = (4 * t + 2 * ks2 + hi) ^ (row & 7);
                    bf16x8 vf = *(const bf16x8*)&Vc[(row * 8 + ch) * 8];
                    oacc[d] = __builtin_amdgcn_mfma_f32_32x32x16_bf16(vf, pu.v, oacc[d], 0, 0, 0);
                }
            }
        }
        __syncthreads();
        cb ^= 1;
    }

    // epilogue: unnormalized O (bf16) + (m,l)
    unsigned short* op = Opart + (size_t)z * MTOK * DD + (size_t)(b * SS + q0 + l31) * DD + h * 64;
#pragma unroll
    for (int d = 0; d < 2; ++d) {
#pragma unroll
        for (int blk = 0; blk < 4; ++blk) {
            unsigned long long pk =
                  (unsigned long long)f2bf(oacc[d][4 * blk + 0])
                | ((unsigned long long)f2bf(oacc[d][4 * blk + 1]) << 16)
                | ((unsigned long long)f2bf(oacc[d][4 * blk + 2]) << 32)
                | ((unsigned long long)f2bf(oacc[d][4 * blk + 3]) << 48);
            *(unsigned long long*)(op + 32 * d + 8 * blk + 4 * hi) = pk;
        }
    }
    if (hi == 0) {
        size_t mi = (((size_t)z * BB * HH + bh) * SS + (q0 + l31)) * 2;
        ML[mi] = m_run;
        ML[mi + 1] = l_run;
    }
}

// ---------------------------------------------------------------------------
// Combine KVSPL kv-split partials -> Ctx bf16. One block per token row.
// ---------------------------------------------------------------------------
__global__ __launch_bounds__(256) void attn_combine(const unsigned short* __restrict__ Opart,
                                                    const float* __restrict__ ML,
                                                    unsigned short* __restrict__ Ctx) {
    const int row = blockIdx.x;
    const int tid = threadIdx.x;
    const int b = row >> 11, s = row & 2047;
    unsigned short* co = Ctx + (size_t)row * DD;
#pragma unroll
    for (int i = 0; i < 3; ++i) {
        int c = tid + i * 256;
        int h = c >> 6;
        float m[KVSPL], l[KVSPL];
        float M = -1e30f;
#pragma unroll
        for (int zz = 0; zz < KVSPL; ++zz) {
            size_t mi = (((size_t)zz * BB * HH + b * HH + h) * SS + s) * 2;
            m[zz] = ML[mi]; l[zz] = ML[mi + 1];
            M = fmaxf(M, m[zz]);
        }
        float denom = 0.0f, num = 0.0f;
#pragma unroll
        for (int zz = 0; zz < KVSPL; ++zz) {
            float wgt = exp2f(m[zz] - M);
            denom += wgt * l[zz];
            num += wgt * bf2f(Opart[(size_t)zz * MTOK * DD + (size_t)row * DD + c]);
        }
        co[c] = f2bf(num / denom);
    }
}

// ---------------------------------------------------------------------------
__global__ __launch_bounds__(256) void v_transpose(const unsigned short* __restrict__ QKV,
                                                   unsigned short* __restrict__ Vt) {
    __shared__ unsigned short t[64][66];
    const int tid = threadIdx.x;
    const int bh = blockIdx.y, b = bh / HH, h = bh % HH;
    const int s0 = blockIdx.x * 64;
    const int c = tid & 63, r0 = tid >> 6;
#pragma unroll
    for (int i = 0; i < 16; ++i) {
        int r = i * 4 + r0;
        t[r][c] = QKV[(size_t)(b * SS + s0 + r) * 2304 + 1536 + h * 64 + c];
    }
    __syncthreads();
#pragma unroll
    for (int i = 0; i < 16; ++i) {
        int r = i * 4 + r0;   // dh
        Vt[((size_t)bh * 64 + r) * SS + s0 + c] = t[c][r];
    }
}

__global__ __launch_bounds__(256) void wtrans(const float* __restrict__ W,
                                              unsigned short* __restrict__ Wt,
                                              int K, int N, int rowoff) {
    __shared__ float t[32][33];
    const int tid = threadIdx.x;
    const int k0 = blockIdx.x * 32, n0 = blockIdx.y * 32;
    const int c = tid & 31, r0 = tid >> 5;
#pragma unroll
    for (int i = 0; i < 4; ++i) {
        int r = i * 8 + r0;
        t[r][c] = W[(size_t)(k0 + r) * N + n0 + c];
    }
    __syncthreads();
#pragma unroll
    for (int i = 0; i < 4; ++i) {
        int r = i * 8 + r0;
        Wt[(size_t)(rowoff + n0 + r) * K + k0 + c] = f2bf(t[c][r]);
    }
}

__global__ __launch_bounds__(256) void f2b_vec(const float* __restrict__ in,
                                               unsigned short* __restrict__ out, int n4) {
    int i = blockIdx.x * 256 + threadIdx.x;
    if (i < n4) {
        float4 v = ((const float4*)in)[i];
        unsigned long long pk = (unsigned long long)f2bf(v.x)
                              | ((unsigned long long)f2bf(v.y) << 16)
                              | ((unsigned long long)f2bf(v.z) << 32)
                              | ((unsigned long long)f2bf(v.w) << 48);
        ((unsigned long long*)out)[i] = pk;
    }
}

__global__ __launch_bounds__(256) void bias_concat(const float* __restrict__ q,
                                                   const float* __restrict__ k,
                                                   const float* __restrict__ v,
                                                   float* __restrict__ o) {
    int i = blockIdx.x * 256 + threadIdx.x;
    if (i < DD) { o[i] = q[i]; o[DD + i] = k[i]; o[2 * DD + i] = v[i]; }
}

// ---------------------------------------------------------------------------
// out_f = LayerNorm(a + p1 + p2 + bias)*g + be ; WB=1 also writes bf16 copy
// ---------------------------------------------------------------------------
template <int WB>
__global__ __launch_bounds__(256) void add_ln3(const float* __restrict__ a,
                                               const float* __restrict__ p1,
                                               const float* __restrict__ p2,
                                               const float* __restrict__ bias,
                                               const float* __restrict__ g,
                                               const float* __restrict__ be,
                                               float* __restrict__ outf,
                                               unsigned short* __restrict__ outb) {
    const int row = blockIdx.x;
    const int tid = threadIdx.x;
    float x[3];
    float s = 0.0f, s2 = 0.0f;
#pragma unroll
    for (int i = 0; i < 3; ++i) {
        int c = tid + i * 256;
        size_t idx = (size_t)row * DD + c;
        float v = a[idx] + p1[idx] + p2[idx] + bias[c];
        x[i] = v; s += v; s2 += v * v;
    }
#pragma unroll
    for (int off = 32; off; off >>= 1) {
        s += __shfl_down(s, off);
        s2 += __shfl_down(s2, off);
    }
    __shared__ float ws[8];
    const int wid = tid >> 6, lane = tid & 63;
    if (lane == 0) { ws[wid] = s; ws[4 + wid] = s2; }
    __syncthreads();
    if (tid == 0) {
        ws[0] = ws[0] + ws[1] + ws[2] + ws[3];
        ws[4] = ws[4] + ws[5] + ws[6] + ws[7];
    }
    __syncthreads();
    const float mean = ws[0] * (1.0f / DD);
    const float var = ws[4] * (1.0f / DD) - mean * mean;
    const float inv = rsqrtf(var + 1e-5f);
#pragma unroll
    for (int i = 0; i < 3; ++i) {
        int c = tid + i * 256;
        float res = (x[i] - mean) * inv * g[c] + be[c];
        outf[(size_t)row * DD + c] = res;
        if (WB) outb[(size_t)row * DD + c] = f2bf(res);
    }
}

// ---------------------------------------------------------------------------
extern "C" void kernel_launch(void* const* d_in, const int* in_sizes, int n_in,
                              void* d_out, int out_size, void* d_ws, size_t ws_size,
                              hipStream_t stream) {
    const float* x   = (const float*)d_in[0];
    const float* Wq  = (const float*)d_in[1];
    const float* bq  = (const float*)d_in[2];
    const float* Wk  = (const float*)d_in[3];
    const float* bk  = (const float*)d_in[4];
    const float* Wv  = (const float*)d_in[5];
    const float* bv  = (const float*)d_in[6];
    const float* Wo  = (const float*)d_in[7];
    const float* bo  = (const float*)d_in[8];
    const float* W1  = (const float*)d_in[9];
    const float* b1  = (const float*)d_in[10];
    const float* W2  = (const float*)d_in[11];
    const float* b2  = (const float*)d_in[12];
    const float* g1  = (const float*)d_in[13];
    const float* be1 = (const float*)d_in[14];
    const float* g2  = (const float*)d_in[15];
    const float* be2 = (const float*)d_in[16];
    float* out = (float*)d_out;

    char* w8 = (char*)d_ws;
    unsigned short* QKV = (unsigned short*)w8;                      // 18874368 B
    unsigned short* Hff = (unsigned short*)w8;                      // overlays after LN1
    unsigned short* Vt  = (unsigned short*)(w8 + 18874368);         // 6291456
    unsigned short* Ctxb  = (unsigned short*)(w8 + 25165824);       // 6291456
    unsigned short* xb    = (unsigned short*)(w8 + 31457280);       // 6291456 (also X2b)
    unsigned short* Wqkvt = (unsigned short*)(w8 + 37748736);       // 3538944
    unsigned short* Wot   = (unsigned short*)(w8 + 41287680);       // 1179648
    unsigned short* W1t   = (unsigned short*)(w8 + 42467328);       // 4718592
    unsigned short* W2t   = (unsigned short*)(w8 + 47185920);       // 4718592
    float* bqkv = (float*)(w8 + 51904512);                          // 9216 (+pad)
    unsigned short* Ob = (unsigned short*)(w8 + 51916800);          // KVSPL*6291456 = 25165824
    float* Pa   = (float*)(w8 + 51916800);                          // 12582912 (GEMM partial z=0)
    float* Pb   = (float*)(w8 + 64499712);                          // 12582912 (GEMM partial z=1)
    float* X2   = (float*)(w8 + 77082624);                          // 12582912
    float* ML   = (float*)(w8 + 89665536);                          // KVSPL*393216 = 1572864

    dim3 blk(256);

    // prep: conversions / transposes
    f2b_vec<<<dim3(3072), blk, 0, stream>>>(x, xb, MTOK * DD / 4);
    wtrans<<<dim3(24, 24), blk, 0, stream>>>(Wq, Wqkvt, DD, DD, 0);
    wtrans<<<dim3(24, 24), blk, 0, stream>>>(Wk, Wqkvt, DD, DD, DD);
    wtrans<<<dim3(24, 24), blk, 0, stream>>>(Wv, Wqkvt, DD, DD, 2 * DD);
    wtrans<<<dim3(24, 24), blk, 0, stream>>>(Wo, Wot, DD, DD, 0);
    wtrans<<<dim3(24, 96), blk, 0, stream>>>(W1, W1t, DD, DFFN, 0);
    wtrans<<<dim3(96, 24), blk, 0, stream>>>(W2, W2t, DFFN, DD, 0);
    bias_concat<<<dim3(3), blk, 0, stream>>>(bq, bk, bv, bqkv);

    // fused QKV projection -> QKV bf16 [4096][2304]
    gemm_mfma<0, 1><<<dim3(32, 18, 1), blk, 0, stream>>>(xb, Wqkvt, bqkv, QKV,
                                                         MTOK, 3 * DD, DD, DD, DD);
    // V transpose -> Vt [24][64][2048]
    v_transpose<<<dim3(32, 24), blk, 0, stream>>>(QKV, Vt);
    // attention, kv-split=4 -> Ob (unnormalized bf16) + ML
    attn_mfma4<<<dim3(SS / 128, BB * HH, KVSPL), blk, 0, stream>>>(QKV, Vt, Ob, ML);
    // combine -> Ctxb bf16
    attn_combine<<<dim3(MTOK), blk, 0, stream>>>(Ob, ML, Ctxb);
    // output projection, split-K=2 in ONE launch -> Pa/Pb
    gemm_mfma<0, 0><<<dim3(32, 6, 2), blk, 0, stream>>>(Ctxb, Wot, nullptr, Pa,
                                                        MTOK, DD, DD, DD, 384);
    // residual + Wo-partials + bias + LN1 -> X2 fp32 + X2b bf16 (xb region)
    add_ln3<1><<<dim3(MTOK), blk, 0, stream>>>(x, Pa, Pb, bo, g1, be1, X2, xb);
    // FFN1 + GELU -> Hff bf16
    gemm_mfma<1, 1><<<dim3(32, 24, 1), blk, 0, stream>>>(xb, W1t, b1, Hff,
                                                         MTOK, DFFN, DD, DD, DD);
    // FFN2, split-K=2 in ONE launch -> Pa/Pb
    gemm_mfma<0, 0><<<dim3(32, 6, 2), blk, 0, stream>>>(Hff, W2t, nullptr, Pa,
                                                        MTOK, DD, DFFN, DFFN, 1536);
    // residual + FFN2-partials + bias + LN2 -> out
    add_ln3<0><<<dim3(MTOK), blk, 0, stream>>>(X2, Pa, Pb, b2, g2, be2, out, nullptr);
}

// Round 12
// 333.647 us; speedup vs baseline: 1.1607x; 1.0345x over previous
//
#include <hip/hip_runtime.h>
#include <math.h>

#define BB 2
#define SS 2048
#define DD 768
#define HH 12
#define DHH 64
#define DFFN 3072
#define MTOK (BB*SS)   // 4096
#define KVSPL 4

typedef __attribute__((ext_vector_type(8))) __bf16 bf16x8;
typedef __attribute__((ext_vector_type(4))) float f32x4;
typedef __attribute__((ext_vector_type(16))) float f32x16;

__device__ __forceinline__ unsigned short f2bf(float f) {
    unsigned int b = __builtin_bit_cast(unsigned int, f);
    b += 0x7FFFu + ((b >> 16) & 1u);           // RNE
    return (unsigned short)(b >> 16);
}
__device__ __forceinline__ float bf2f(unsigned short u) {
    unsigned int b = ((unsigned int)u) << 16;
    return __builtin_bit_cast(float, b);
}

// packed bf16 convert: dst.lo = bf16(lo), dst.hi = bf16(hi), RNE (T12 recipe)
__device__ __forceinline__ unsigned int cvt_pk_bf16(float lo, float hi) {
    unsigned int r;
    asm("v_cvt_pk_bf16_f32 %0, %1, %2" : "=v"(r) : "v"(lo), "v"(hi));
    return r;
}

__device__ __forceinline__ void gload_lds16(const void* g, void* l) {
    __builtin_amdgcn_global_load_lds((const __attribute__((address_space(1))) unsigned int*)g,
                                     (__attribute__((address_space(3))) unsigned int*)l,
                                     16, 0, 0);
}

// ---------------------------------------------------------------------------
// Cross-half (lane i <-> i+32) exchange via v_permlane32_swap_b32 (VALU pipe).
// pswap(X,Y): r0 = {X.lo_half, Y.lo_half}, r1 = {X.hi_half, Y.hi_half}.
// ---------------------------------------------------------------------------
#if __has_builtin(__builtin_amdgcn_permlane32_swap)
__device__ __forceinline__ void pswap(unsigned int x, unsigned int y,
                                      unsigned int& r0, unsigned int& r1) {
    auto r = __builtin_amdgcn_permlane32_swap(x, y, false, false);
    r0 = r[0]; r1 = r[1];
}
#else
__device__ __forceinline__ void pswap(unsigned int x, unsigned int y,
                                      unsigned int& r0, unsigned int& r1) {
    unsigned int xs = __shfl_xor(x, 32);
    unsigned int ys = __shfl_xor(y, 32);
    bool hi = (threadIdx.x & 32) != 0;
    r0 = hi ? ys : x;
    r1 = hi ? y : xs;
}
#endif

__device__ __forceinline__ float xhalf_max(float v) {
    unsigned int u = __builtin_bit_cast(unsigned int, v);
    unsigned int a, b;
    pswap(u, u, a, b);
    return fmaxf(__builtin_bit_cast(float, a), __builtin_bit_cast(float, b));
}
__device__ __forceinline__ float xhalf_sum(float v) {
    unsigned int u = __builtin_bit_cast(unsigned int, v);
    unsigned int a, b;
    pswap(u, u, a, b);
    return __builtin_bit_cast(float, a) + __builtin_bit_cast(float, b);
}

// ---------------------------------------------------------------------------
// bf16 MFMA GEMM: C[M,N] = A[M,K](bf16) @ Bt[N,K](bf16)^T + bias
// 128x128 tile, BK=64, 4 waves. Prefetch double-buffered LDS, ONE barrier
// per K-step. blockIdx.z = K-split index (fp32 out offset z*M*N).
// ---------------------------------------------------------------------------
template <int ACT, int OBF>
__global__ __launch_bounds__(256) void gemm_mfma(const unsigned short* __restrict__ A,
                                                 const unsigned short* __restrict__ Bt,
                                                 const float* __restrict__ bias,
                                                 void* __restrict__ Cout,
                                                 int M, int N, int ldA, int ldB, int Klen) {
    __shared__ unsigned short As[2 * 128 * 64];
    __shared__ unsigned short Bs[2 * 128 * 64];
    const int tid = threadIdx.x;
    const int lane = tid & 63;
    const int w = tid >> 6;
    const int l15 = lane & 15, l4 = lane >> 4;
    const int m0 = blockIdx.x * 128;
    const int n0 = blockIdx.y * 128;
    const int z = blockIdx.z;
    const int wr = (w >> 1) * 64;
    const int wc = (w & 1) * 64;

    const unsigned short* Az = A + (size_t)z * Klen;
    const unsigned short* Bz = Bt + (size_t)z * Klen;

    f32x4 acc[4][4] = {};

    int srow[4], scd[4];
#pragma unroll
    for (int i = 0; i < 4; ++i) {
        int s = w * 256 + i * 64 + lane;
        srow[i] = s >> 3;
        scd[i] = (((s & 7) ^ (srow[i] & 7))) * 8;
    }

#pragma unroll
    for (int i = 0; i < 4; ++i) {
        gload_lds16(Az + (size_t)(m0 + srow[i]) * ldA + scd[i], &As[(w * 256 + i * 64) * 8]);
        gload_lds16(Bz + (size_t)(n0 + srow[i]) * ldB + scd[i], &Bs[(w * 256 + i * 64) * 8]);
    }
    __syncthreads();

    int cb = 0;
    for (int k0 = 0; k0 < Klen; k0 += 64) {
        if (k0 + 64 < Klen) {
            const int nb = (cb ^ 1) * 128 * 64;
#pragma unroll
            for (int i = 0; i < 4; ++i) {
                gload_lds16(Az + (size_t)(m0 + srow[i]) * ldA + k0 + 64 + scd[i],
                            &As[nb + (w * 256 + i * 64) * 8]);
                gload_lds16(Bz + (size_t)(n0 + srow[i]) * ldB + k0 + 64 + scd[i],
                            &Bs[nb + (w * 256 + i * 64) * 8]);
            }
        }
        const unsigned short* Ac = &As[cb * 128 * 64];
        const unsigned short* Bc = &Bs[cb * 128 * 64];
#pragma unroll
        for (int ks = 0; ks < 2; ++ks) {
            bf16x8 af[4], bfr[4];
#pragma unroll
            for (int m = 0; m < 4; ++m) {
                int r = wr + m * 16 + l15;
                int c = (ks * 4 + l4) ^ (r & 7);
                af[m] = *(const bf16x8*)&Ac[(r * 8 + c) * 8];
            }
#pragma unroll
            for (int n = 0; n < 4; ++n) {
                int r = wc + n * 16 + l15;
                int c = (ks * 4 + l4) ^ (r & 7);
                bfr[n] = *(const bf16x8*)&Bc[(r * 8 + c) * 8];
            }
#pragma unroll
            for (int m = 0; m < 4; ++m)
#pragma unroll
                for (int n = 0; n < 4; ++n)
                    acc[m][n] = __builtin_amdgcn_mfma_f32_16x16x32_bf16(af[m], bfr[n], acc[m][n], 0, 0, 0);
        }
        __syncthreads();
        cb ^= 1;
    }

    const size_t zoff = (size_t)z * M * N;
#pragma unroll
    for (int n = 0; n < 4; ++n) {
        int col = n0 + wc + n * 16 + l15;
        float bv = bias ? bias[col] : 0.0f;
#pragma unroll
        for (int m = 0; m < 4; ++m) {
#pragma unroll
            for (int r = 0; r < 4; ++r) {
                int row = m0 + wr + m * 16 + l4 * 4 + r;
                float v = acc[m][n][r] + bv;
                if (ACT) v = 0.5f * v * (1.0f + erff(v * 0.70710678118654752f));
                if (OBF) ((unsigned short*)Cout)[(size_t)row * N + col] = f2bf(v);
                else     ((float*)Cout)[zoff + (size_t)row * N + col] = v;
            }
        }
    }
}

// ---------------------------------------------------------------------------
// MFMA flash attention, kv-split=KVSPL (blockIdx.z), prefetch double-buffer.
// Block = 128 q-rows of one (b,h); 4 waves x 32 q-rows; z covers SS/KVSPL kv.
// Outputs UNNORMALIZED O (bf16) + per-row (m,l) exp2-domain -> attn_combine.
// P packing via v_cvt_pk_bf16_f32; cross-half exchange via permlane32_swap.
// ---------------------------------------------------------------------------
__global__ __launch_bounds__(256) void attn_mfma5(const unsigned short* __restrict__ QKV,
                                                  const unsigned short* __restrict__ Vt,
                                                  unsigned short* __restrict__ Opart, // [KVSPL][4096][768]
                                                  float* __restrict__ ML) {           // [KVSPL][24][2048][2]
    __shared__ unsigned short Ks[2 * 64 * 64];
    __shared__ unsigned short Vs[2 * 64 * 64];
    const int tid = threadIdx.x;
    const int lane = tid & 63;
    const int w = tid >> 6;
    const int l31 = lane & 31;
    const int hi = lane >> 5;
    const int bh = blockIdx.y;
    const int b = bh / HH, h = bh % HH;
    const int z = blockIdx.z;
    const int q0 = blockIdx.x * 128 + w * 32;
    const float CLOG = 0.18033688011112042f;   // 0.125 * log2(e)

    bf16x8 qf[4];
    {
        const unsigned short* qp = QKV + (size_t)(b * SS + q0 + l31) * 2304 + h * 64 + hi * 8;
        qf[0] = *(const bf16x8*)qp;
        qf[1] = *(const bf16x8*)(qp + 16);
        qf[2] = *(const bf16x8*)(qp + 32);
        qf[3] = *(const bf16x8*)(qp + 48);
    }

    f32x16 oacc[2] = {};
    float m_run = -1e30f, l_run = 0.0f;

    int arow[2], acd[2];
#pragma unroll
    for (int i = 0; i < 2; ++i) {
        int s = w * 128 + i * 64 + lane;
        arow[i] = s >> 3;
        acd[i] = ((s & 7) ^ (arow[i] & 7)) * 8;
    }

    const int kbase = z * (SS / KVSPL);
#pragma unroll
    for (int i = 0; i < 2; ++i) {
        gload_lds16(QKV + (size_t)(b * SS + kbase + arow[i]) * 2304 + DD + h * 64 + acd[i],
                    &Ks[(w * 128 + i * 64) * 8]);
        gload_lds16(Vt + (size_t)(bh * 64 + arow[i]) * SS + kbase + acd[i],
                    &Vs[(w * 128 + i * 64) * 8]);
    }
    __syncthreads();

    int cb = 0;
    const int NT = (SS / KVSPL) / 64;
    for (int it = 0; it < NT; ++it) {
        if (it + 1 < NT) {
            const int k0n = kbase + (it + 1) * 64;
            const int nb = (cb ^ 1) * 64 * 64;
#pragma unroll
            for (int i = 0; i < 2; ++i) {
                gload_lds16(QKV + (size_t)(b * SS + k0n + arow[i]) * 2304 + DD + h * 64 + acd[i],
                            &Ks[nb + (w * 128 + i * 64) * 8]);
                gload_lds16(Vt + (size_t)(bh * 64 + arow[i]) * SS + k0n + acd[i],
                            &Vs[nb + (w * 128 + i * 64) * 8]);
            }
        }
        const unsigned short* Kc = &Ks[cb * 64 * 64];
        const unsigned short* Vc = &Vs[cb * 64 * 64];

        // S^T tiles: st[t][r] = S[kv=32t+(r&3)+8*(r>>2)+4*hi][q=l31]
        f32x16 st[2] = {};
#pragma unroll
        for (int t = 0; t < 2; ++t) {
#pragma unroll
            for (int ks = 0; ks < 4; ++ks) {
                int row = 32 * t + l31;
                int ch = (2 * ks + hi) ^ (row & 7);
                bf16x8 kf = *(const bf16x8*)&Kc[(row * 8 + ch) * 8];
                st[t] = __builtin_amdgcn_mfma_f32_32x32x16_bf16(kf, qf[ks], st[t], 0, 0, 0);
            }
        }

        // row max over lane's 32 values (max3-fusable tree) + cross-half
        float pmax = fmaxf(st[0][0], fmaxf(st[0][1], st[0][2]));
#pragma unroll
        for (int r = 3; r < 15; r += 2) pmax = fmaxf(pmax, fmaxf(st[0][r], st[0][r + 1]));
        pmax = fmaxf(pmax, st[0][15]);
#pragma unroll
        for (int r = 0; r < 16; r += 2) pmax = fmaxf(pmax, fmaxf(st[1][r], st[1][r + 1]));
        pmax = xhalf_max(pmax) * CLOG;

        // defer-max: rescale only when some row grew by > 8
        if (!__all(pmax <= m_run + 8.0f)) {
            float mn = fmaxf(m_run, pmax);
            float corr = exp2f(m_run - mn);
#pragma unroll
            for (int d = 0; d < 2; ++d)
#pragma unroll
                for (int r = 0; r < 16; ++r) oacc[d][r] *= corr;
            l_run *= corr;
            m_run = mn;
        }

        // p = exp2(s*CLOG - m_run); pack bf16 via cvt_pk; row-sum
        unsigned int Wn[2][4][2];
        float rs = 0.0f;
#pragma unroll
        for (int t = 0; t < 2; ++t) {
#pragma unroll
            for (int blk = 0; blk < 4; ++blk) {
                float pa = exp2f(fmaf(st[t][4 * blk + 0], CLOG, -m_run));
                float pb = exp2f(fmaf(st[t][4 * blk + 1], CLOG, -m_run));
                float pc = exp2f(fmaf(st[t][4 * blk + 2], CLOG, -m_run));
                float pd = exp2f(fmaf(st[t][4 * blk + 3], CLOG, -m_run));
                rs += (pa + pb) + (pc + pd);
                Wn[t][blk][0] = cvt_pk_bf16(pa, pb);
                Wn[t][blk][1] = cvt_pk_bf16(pc, pd);
            }
        }
        l_run += xhalf_sum(rs);

        // PV: O^T += V^T @ P^T. P^T B-fragment via pswap:
        // pswap(X,Y) -> r0 = {X.lo,Y.lo} (u[0..1] src), r1 = {X.hi,Y.hi}
#pragma unroll
        for (int t = 0; t < 2; ++t) {
#pragma unroll
            for (int ks2 = 0; ks2 < 2; ++ks2) {
                unsigned int a0, a1, b0, b1;
                pswap(Wn[t][2 * ks2][0], Wn[t][2 * ks2 + 1][0], a0, a1);
                pswap(Wn[t][2 * ks2][1], Wn[t][2 * ks2 + 1][1], b0, b1);
                union { unsigned int u[4]; bf16x8 v; } pu;
                pu.u[0] = a0; pu.u[1] = b0;
                pu.u[2] = a1; pu.u[3] = b1;
#pragma unroll
                for (int d = 0; d < 2; ++d) {
                    int row = 32 * d + l31;
                    int ch = (4 * t + 2 * ks2 + hi) ^ (row & 7);
                    bf16x8 vf = *(const bf16x8*)&Vc[(row * 8 + ch) * 8];
                    oacc[d] = __builtin_amdgcn_mfma_f32_32x32x16_bf16(vf, pu.v, oacc[d], 0, 0, 0);
                }
            }
        }
        __syncthreads();
        cb ^= 1;
    }

    // epilogue: unnormalized O (bf16, cvt_pk) + (m,l)
    unsigned short* op = Opart + (size_t)z * MTOK * DD + (size_t)(b * SS + q0 + l31) * DD + h * 64;
#pragma unroll
    for (int d = 0; d < 2; ++d) {
#pragma unroll
        for (int blk = 0; blk < 4; ++blk) {
            unsigned int w0 = cvt_pk_bf16(oacc[d][4 * blk + 0], oacc[d][4 * blk + 1]);
            unsigned int w1 = cvt_pk_bf16(oacc[d][4 * blk + 2], oacc[d][4 * blk + 3]);
            *(unsigned long long*)(op + 32 * d + 8 * blk + 4 * hi) =
                (unsigned long long)w0 | ((unsigned long long)w1 << 32);
        }
    }
    if (hi == 0) {
        size_t mi = (((size_t)z * BB * HH + bh) * SS + (q0 + l31)) * 2;
        ML[mi] = m_run;
        ML[mi + 1] = l_run;
    }
}

// ---------------------------------------------------------------------------
// Combine KVSPL kv-split partials -> Ctx bf16. One block per token row.
// ---------------------------------------------------------------------------
__global__ __launch_bounds__(256) void attn_combine(const unsigned short* __restrict__ Opart,
                                                    const float* __restrict__ ML,
                                                    unsigned short* __restrict__ Ctx) {
    const int row = blockIdx.x;
    const int tid = threadIdx.x;
    const int b = row >> 11, s = row & 2047;
    unsigned short* co = Ctx + (size_t)row * DD;
#pragma unroll
    for (int i = 0; i < 3; ++i) {
        int c = tid + i * 256;
        int h = c >> 6;
        float m[KVSPL], l[KVSPL];
        float M = -1e30f;
#pragma unroll
        for (int zz = 0; zz < KVSPL; ++zz) {
            size_t mi = (((size_t)zz * BB * HH + b * HH + h) * SS + s) * 2;
            m[zz] = ML[mi]; l[zz] = ML[mi + 1];
            M = fmaxf(M, m[zz]);
        }
        float denom = 0.0f, num = 0.0f;
#pragma unroll
        for (int zz = 0; zz < KVSPL; ++zz) {
            float wgt = exp2f(m[zz] - M);
            denom += wgt * l[zz];
            num += wgt * bf2f(Opart[(size_t)zz * MTOK * DD + (size_t)row * DD + c]);
        }
        co[c] = f2bf(num / denom);
    }
}

// ---------------------------------------------------------------------------
__global__ __launch_bounds__(256) void v_transpose(const unsigned short* __restrict__ QKV,
                                                   unsigned short* __restrict__ Vt) {
    __shared__ unsigned short t[64][66];
    const int tid = threadIdx.x;
    const int bh = blockIdx.y, b = bh / HH, h = bh % HH;
    const int s0 = blockIdx.x * 64;
    const int c = tid & 63, r0 = tid >> 6;
#pragma unroll
    for (int i = 0; i < 16; ++i) {
        int r = i * 4 + r0;
        t[r][c] = QKV[(size_t)(b * SS + s0 + r) * 2304 + 1536 + h * 64 + c];
    }
    __syncthreads();
#pragma unroll
    for (int i = 0; i < 16; ++i) {
        int r = i * 4 + r0;   // dh
        Vt[((size_t)bh * 64 + r) * SS + s0 + c] = t[c][r];
    }
}

// ---------------------------------------------------------------------------
// Merged prep: one launch does x->bf16, all 6 weight transposes, bias concat.
// Block-range dispatch (uniform per block, no divergence within a block).
// ---------------------------------------------------------------------------
__device__ __forceinline__ void wtrans_body(const float* __restrict__ W,
                                            unsigned short* __restrict__ Wt,
                                            int K, int N, int rowoff,
                                            int k0, int n0, int tid,
                                            float (*t)[33]) {
    const int c = tid & 31, r0 = tid >> 5;
#pragma unroll
    for (int i = 0; i < 4; ++i) {
        int r = i * 8 + r0;
        t[r][c] = W[(size_t)(k0 + r) * N + n0 + c];
    }
    __syncthreads();
#pragma unroll
    for (int i = 0; i < 4; ++i) {
        int r = i * 8 + r0;
        Wt[(size_t)(rowoff + n0 + r) * K + k0 + c] = f2bf(t[c][r]);
    }
}

__global__ __launch_bounds__(256) void prep_all(const float* __restrict__ x,
                                                unsigned short* __restrict__ xb,
                                                const float* __restrict__ Wq,
                                                const float* __restrict__ Wk,
                                                const float* __restrict__ Wv,
                                                const float* __restrict__ Wo,
                                                const float* __restrict__ W1,
                                                const float* __restrict__ W2,
                                                unsigned short* __restrict__ Wqkvt,
                                                unsigned short* __restrict__ Wot,
                                                unsigned short* __restrict__ W1t,
                                                unsigned short* __restrict__ W2t,
                                                const float* __restrict__ bq,
                                                const float* __restrict__ bk,
                                                const float* __restrict__ bv,
                                                float* __restrict__ bqkv) {
    __shared__ float t[32][33];
    const int bid = blockIdx.x;
    const int tid = threadIdx.x;
    if (bid < 3072) {                       // x -> xb (bf16), 4 f32/thread
        int i = bid * 256 + tid;            // i < 786432
        float4 v = ((const float4*)x)[i];
        unsigned long long pk = (unsigned long long)f2bf(v.x)
                              | ((unsigned long long)f2bf(v.y) << 16)
                              | ((unsigned long long)f2bf(v.z) << 32)
                              | ((unsigned long long)f2bf(v.w) << 48);
        ((unsigned long long*)xb)[i] = pk;
    } else if (bid < 3648) {                // Wq (24x24)
        int lb = bid - 3072;
        wtrans_body(Wq, Wqkvt, DD, DD, 0, (lb % 24) * 32, (lb / 24) * 32, tid, t);
    } else if (bid < 4224) {                // Wk
        int lb = bid - 3648;
        wtrans_body(Wk, Wqkvt, DD, DD, DD, (lb % 24) * 32, (lb / 24) * 32, tid, t);
    } else if (bid < 4800) {                // Wv
        int lb = bid - 4224;
        wtrans_body(Wv, Wqkvt, DD, DD, 2 * DD, (lb % 24) * 32, (lb / 24) * 32, tid, t);
    } else if (bid < 5376) {                // Wo
        int lb = bid - 4800;
        wtrans_body(Wo, Wot, DD, DD, 0, (lb % 24) * 32, (lb / 24) * 32, tid, t);
    } else if (bid < 7680) {                // W1 (24x96): K=768, N=3072
        int lb = bid - 5376;
        wtrans_body(W1, W1t, DD, DFFN, 0, (lb % 24) * 32, (lb / 24) * 32, tid, t);
    } else if (bid < 9984) {                // W2 (96x24): K=3072, N=768
        int lb = bid - 7680;
        wtrans_body(W2, W2t, DFFN, DD, 0, (lb % 96) * 32, (lb / 96) * 32, tid, t);
    } else {                                // bias concat (3 blocks)
        int i = (bid - 9984) * 256 + tid;
        if (i < DD) { bqkv[i] = bq[i]; bqkv[DD + i] = bk[i]; bqkv[2 * DD + i] = bv[i]; }
    }
}

// ---------------------------------------------------------------------------
// out_f = LayerNorm(a + p1 + p2 + bias)*g + be ; WB=1 also writes bf16 copy
// ---------------------------------------------------------------------------
template <int WB>
__global__ __launch_bounds__(256) void add_ln3(const float* __restrict__ a,
                                               const float* __restrict__ p1,
                                               const float* __restrict__ p2,
                                               const float* __restrict__ bias,
                                               const float* __restrict__ g,
                                               const float* __restrict__ be,
                                               float* __restrict__ outf,
                                               unsigned short* __restrict__ outb) {
    const int row = blockIdx.x;
    const int tid = threadIdx.x;
    float x[3];
    float s = 0.0f, s2 = 0.0f;
#pragma unroll
    for (int i = 0; i < 3; ++i) {
        int c = tid + i * 256;
        size_t idx = (size_t)row * DD + c;
        float v = a[idx] + p1[idx] + p2[idx] + bias[c];
        x[i] = v; s += v; s2 += v * v;
    }
#pragma unroll
    for (int off = 32; off; off >>= 1) {
        s += __shfl_down(s, off);
        s2 += __shfl_down(s2, off);
    }
    __shared__ float ws[8];
    const int wid = tid >> 6, lane = tid & 63;
    if (lane == 0) { ws[wid] = s; ws[4 + wid] = s2; }
    __syncthreads();
    if (tid == 0) {
        ws[0] = ws[0] + ws[1] + ws[2] + ws[3];
        ws[4] = ws[4] + ws[5] + ws[6] + ws[7];
    }
    __syncthreads();
    const float mean = ws[0] * (1.0f / DD);
    const float var = ws[4] * (1.0f / DD) - mean * mean;
    const float inv = rsqrtf(var + 1e-5f);
#pragma unroll
    for (int i = 0; i < 3; ++i) {
        int c = tid + i * 256;
        float res = (x[i] - mean) * inv * g[c] + be[c];
        outf[(size_t)row * DD + c] = res;
        if (WB) outb[(size_t)row * DD + c] = f2bf(res);
    }
}

// ---------------------------------------------------------------------------
extern "C" void kernel_launch(void* const* d_in, const int* in_sizes, int n_in,
                              void* d_out, int out_size, void* d_ws, size_t ws_size,
                              hipStream_t stream) {
    const float* x   = (const float*)d_in[0];
    const float* Wq  = (const float*)d_in[1];
    const float* bq  = (const float*)d_in[2];
    const float* Wk  = (const float*)d_in[3];
    const float* bk  = (const float*)d_in[4];
    const float* Wv  = (const float*)d_in[5];
    const float* bv  = (const float*)d_in[6];
    const float* Wo  = (const float*)d_in[7];
    const float* bo  = (const float*)d_in[8];
    const float* W1  = (const float*)d_in[9];
    const float* b1  = (const float*)d_in[10];
    const float* W2  = (const float*)d_in[11];
    const float* b2  = (const float*)d_in[12];
    const float* g1  = (const float*)d_in[13];
    const float* be1 = (const float*)d_in[14];
    const float* g2  = (const float*)d_in[15];
    const float* be2 = (const float*)d_in[16];
    float* out = (float*)d_out;

    char* w8 = (char*)d_ws;
    unsigned short* QKV = (unsigned short*)w8;                      // 18874368 B
    unsigned short* Hff = (unsigned short*)w8;                      // overlays after LN1
    unsigned short* Vt  = (unsigned short*)(w8 + 18874368);         // 6291456
    unsigned short* Ctxb  = (unsigned short*)(w8 + 25165824);       // 6291456
    unsigned short* xb    = (unsigned short*)(w8 + 31457280);       // 6291456 (also X2b)
    unsigned short* Wqkvt = (unsigned short*)(w8 + 37748736);       // 3538944
    unsigned short* Wot   = (unsigned short*)(w8 + 41287680);       // 1179648
    unsigned short* W1t   = (unsigned short*)(w8 + 42467328);       // 4718592
    unsigned short* W2t   = (unsigned short*)(w8 + 47185920);       // 4718592
    float* bqkv = (float*)(w8 + 51904512);                          // 9216 (+pad)
    unsigned short* Ob = (unsigned short*)(w8 + 51916800);          // KVSPL*6291456 = 25165824
    float* Pa   = (float*)(w8 + 51916800);                          // 12582912 (GEMM partial z=0)
    float* Pb   = (float*)(w8 + 64499712);                          // 12582912 (GEMM partial z=1)
    float* X2   = (float*)(w8 + 77082624);                          // 12582912
    float* ML   = (float*)(w8 + 89665536);                          // KVSPL*393216 = 1572864

    dim3 blk(256);

    // merged prep: x->bf16, 6 weight transposes, bias concat (ONE launch)
    prep_all<<<dim3(9987), blk, 0, stream>>>(x, xb, Wq, Wk, Wv, Wo, W1, W2,
                                             Wqkvt, Wot, W1t, W2t, bq, bk, bv, bqkv);

    // fused QKV projection -> QKV bf16 [4096][2304]
    gemm_mfma<0, 1><<<dim3(32, 18, 1), blk, 0, stream>>>(xb, Wqkvt, bqkv, QKV,
                                                         MTOK, 3 * DD, DD, DD, DD);
    // V transpose -> Vt [24][64][2048]
    v_transpose<<<dim3(32, 24), blk, 0, stream>>>(QKV, Vt);
    // attention, kv-split=4 -> Ob (unnormalized bf16) + ML
    attn_mfma5<<<dim3(SS / 128, BB * HH, KVSPL), blk, 0, stream>>>(QKV, Vt, Ob, ML);
    // combine -> Ctxb bf16
    attn_combine<<<dim3(MTOK), blk, 0, stream>>>(Ob, ML, Ctxb);
    // output projection, split-K=2 in ONE launch -> Pa/Pb
    gemm_mfma<0, 0><<<dim3(32, 6, 2), blk, 0, stream>>>(Ctxb, Wot, nullptr, Pa,
                                                        MTOK, DD, DD, DD, 384);
    // residual + Wo-partials + bias + LN1 -> X2 fp32 + X2b bf16 (xb region)
    add_ln3<1><<<dim3(MTOK), blk, 0, stream>>>(x, Pa, Pb, bo, g1, be1, X2, xb);
    // FFN1 + GELU -> Hff bf16
    gemm_mfma<1, 1><<<dim3(32, 24, 1), blk, 0, stream>>>(xb, W1t, b1, Hff,
                                                         MTOK, DFFN, DD, DD, DD);
    // FFN2, split-K=2 in ONE launch -> Pa/Pb
    gemm_mfma<0, 0><<<dim3(32, 6, 2), blk, 0, stream>>>(Hff, W2t, nullptr, Pa,
                                                        MTOK, DD, DFFN, DFFN, 1536);
    // residual + FFN2-partials + bias + LN2 -> out
    add_ln3<0><<<dim3(MTOK), blk, 0, stream>>>(X2, Pa, Pb, b2, g2, be2, out, nullptr);
}

// Round 14
// 310.655 us; speedup vs baseline: 1.2466x; 1.0740x over previous
//
#include <hip/hip_runtime.h>
#include <math.h>

#define BB 2
#define SS 2048
#define DD 768
#define HH 12
#define DHH 64
#define DFFN 3072
#define MTOK (BB*SS)   // 4096
#define KVSPL 4

typedef __attribute__((ext_vector_type(8))) __bf16 bf16x8;
typedef __attribute__((ext_vector_type(4))) float f32x4;
typedef __attribute__((ext_vector_type(16))) float f32x16;

__device__ __forceinline__ unsigned short f2bf(float f) {
    unsigned int b = __builtin_bit_cast(unsigned int, f);
    b += 0x7FFFu + ((b >> 16) & 1u);           // RNE
    return (unsigned short)(b >> 16);
}
__device__ __forceinline__ float bf2f(unsigned short u) {
    unsigned int b = ((unsigned int)u) << 16;
    return __builtin_bit_cast(float, b);
}

// packed bf16 convert: dst.lo = bf16(lo), dst.hi = bf16(hi), RNE (T12 recipe)
__device__ __forceinline__ unsigned int cvt_pk_bf16(float lo, float hi) {
    unsigned int r;
    asm("v_cvt_pk_bf16_f32 %0, %1, %2" : "=v"(r) : "v"(lo), "v"(hi));
    return r;
}

__device__ __forceinline__ void gload_lds16(const void* g, void* l) {
    __builtin_amdgcn_global_load_lds((const __attribute__((address_space(1))) unsigned int*)g,
                                     (__attribute__((address_space(3))) unsigned int*)l,
                                     16, 0, 0);
}

// ---------------------------------------------------------------------------
// Cross-half (lane i <-> i+32) exchange via v_permlane32_swap_b32 (VALU pipe).
// pswap(X,Y): r0 = {X.lo_half, Y.lo_half}, r1 = {X.hi_half, Y.hi_half}.
// ---------------------------------------------------------------------------
#if __has_builtin(__builtin_amdgcn_permlane32_swap)
__device__ __forceinline__ void pswap(unsigned int x, unsigned int y,
                                      unsigned int& r0, unsigned int& r1) {
    auto r = __builtin_amdgcn_permlane32_swap(x, y, false, false);
    r0 = r[0]; r1 = r[1];
}
#else
__device__ __forceinline__ void pswap(unsigned int x, unsigned int y,
                                      unsigned int& r0, unsigned int& r1) {
    unsigned int xs = __shfl_xor(x, 32);
    unsigned int ys = __shfl_xor(y, 32);
    bool hi = (threadIdx.x & 32) != 0;
    r0 = hi ? ys : x;
    r1 = hi ? y : xs;
}
#endif

__device__ __forceinline__ float xhalf_max(float v) {
    unsigned int u = __builtin_bit_cast(unsigned int, v);
    unsigned int a, b;
    pswap(u, u, a, b);
    return fmaxf(__builtin_bit_cast(float, a), __builtin_bit_cast(float, b));
}
__device__ __forceinline__ float xhalf_sum(float v) {
    unsigned int u = __builtin_bit_cast(unsigned int, v);
    unsigned int a, b;
    pswap(u, u, a, b);
    return __builtin_bit_cast(float, a) + __builtin_bit_cast(float, b);
}

// ---------------------------------------------------------------------------
// bf16 MFMA GEMM: C[M,N] = A[M,K](bf16) @ Bt[N,K](bf16)^T + bias
// 128x128 tile, BK=64, 4 waves. SINGLE-buffer 32KB LDS, 2-barrier loop
// (m97 structure — 64KB dbuf measured as occupancy regression, m132).
// blockIdx.z = K-split index; fp32 partial target selected per z
// (P0/P1/P2 — partials are not contiguous in workspace).
// ---------------------------------------------------------------------------
template <int ACT, int OBF>
__global__ __launch_bounds__(256) void gemm_mfma(const unsigned short* __restrict__ A,
                                                 const unsigned short* __restrict__ Bt,
                                                 const float* __restrict__ bias,
                                                 void* __restrict__ C0,
                                                 float* __restrict__ P1,
                                                 float* __restrict__ P2,
                                                 int M, int N, int ldA, int ldB, int Klen) {
    __shared__ unsigned short As[128 * 64];
    __shared__ unsigned short Bs[128 * 64];
    const int tid = threadIdx.x;
    const int lane = tid & 63;
    const int w = tid >> 6;
    const int l15 = lane & 15, l4 = lane >> 4;
    const int m0 = blockIdx.x * 128;
    const int n0 = blockIdx.y * 128;
    const int z = blockIdx.z;
    const int wr = (w >> 1) * 64;
    const int wc = (w & 1) * 64;

    const unsigned short* Az = A + (size_t)z * Klen;
    const unsigned short* Bz = Bt + (size_t)z * Klen;
    float* Pz = (z == 0) ? (float*)C0 : (z == 1 ? P1 : P2);

    f32x4 acc[4][4] = {};

    int srow[4], scd[4];
#pragma unroll
    for (int i = 0; i < 4; ++i) {
        int s = w * 256 + i * 64 + lane;
        srow[i] = s >> 3;                          // row (0..127), 8 chunks/row
        scd[i] = (((s & 7) ^ (srow[i] & 7))) * 8;  // swizzled source chunk (elems)
    }

    for (int k0 = 0; k0 < Klen; k0 += 64) {
        __syncthreads();
#pragma unroll
        for (int i = 0; i < 4; ++i) {
            gload_lds16(Az + (size_t)(m0 + srow[i]) * ldA + k0 + scd[i],
                        &As[(w * 256 + i * 64) * 8]);
            gload_lds16(Bz + (size_t)(n0 + srow[i]) * ldB + k0 + scd[i],
                        &Bs[(w * 256 + i * 64) * 8]);
        }
        __syncthreads();
#pragma unroll
        for (int ks = 0; ks < 2; ++ks) {
            bf16x8 af[4], bfr[4];
#pragma unroll
            for (int m = 0; m < 4; ++m) {
                int r = wr + m * 16 + l15;
                int c = (ks * 4 + l4) ^ (r & 7);
                af[m] = *(const bf16x8*)&As[(r * 8 + c) * 8];
            }
#pragma unroll
            for (int n = 0; n < 4; ++n) {
                int r = wc + n * 16 + l15;
                int c = (ks * 4 + l4) ^ (r & 7);
                bfr[n] = *(const bf16x8*)&Bs[(r * 8 + c) * 8];
            }
#pragma unroll
            for (int m = 0; m < 4; ++m)
#pragma unroll
                for (int n = 0; n < 4; ++n)
                    acc[m][n] = __builtin_amdgcn_mfma_f32_16x16x32_bf16(af[m], bfr[n], acc[m][n], 0, 0, 0);
        }
    }

#pragma unroll
    for (int n = 0; n < 4; ++n) {
        int col = n0 + wc + n * 16 + l15;
        float bv = bias ? bias[col] : 0.0f;
#pragma unroll
        for (int m = 0; m < 4; ++m) {
#pragma unroll
            for (int r = 0; r < 4; ++r) {
                int row = m0 + wr + m * 16 + l4 * 4 + r;
                float v = acc[m][n][r] + bv;
                if (ACT) v = 0.5f * v * (1.0f + erff(v * 0.70710678118654752f));
                if (OBF) ((unsigned short*)C0)[(size_t)row * N + col] = f2bf(v);
                else     Pz[(size_t)row * N + col] = v;
            }
        }
    }
}

// ---------------------------------------------------------------------------
// MFMA flash attention, kv-split=KVSPL (blockIdx.z), prefetch double-buffer.
// Block = 128 q-rows of one (b,h); 4 waves x 32 q-rows; z covers SS/KVSPL kv.
// Outputs UNNORMALIZED O (bf16) + per-row (m,l) exp2-domain -> attn_combine.
// P packing via v_cvt_pk_bf16_f32; cross-half exchange via permlane32_swap.
// ---------------------------------------------------------------------------
__global__ __launch_bounds__(256) void attn_mfma5(const unsigned short* __restrict__ QKV,
                                                  const unsigned short* __restrict__ Vt,
                                                  unsigned short* __restrict__ Opart, // [KVSPL][4096][768]
                                                  float* __restrict__ ML) {           // [KVSPL][24][2048][2]
    __shared__ unsigned short Ks[2 * 64 * 64];
    __shared__ unsigned short Vs[2 * 64 * 64];
    const int tid = threadIdx.x;
    const int lane = tid & 63;
    const int w = tid >> 6;
    const int l31 = lane & 31;
    const int hi = lane >> 5;
    const int bh = blockIdx.y;
    const int b = bh / HH, h = bh % HH;
    const int z = blockIdx.z;
    const int q0 = blockIdx.x * 128 + w * 32;
    const float CLOG = 0.18033688011112042f;   // 0.125 * log2(e)

    bf16x8 qf[4];
    {
        const unsigned short* qp = QKV + (size_t)(b * SS + q0 + l31) * 2304 + h * 64 + hi * 8;
        qf[0] = *(const bf16x8*)qp;
        qf[1] = *(const bf16x8*)(qp + 16);
        qf[2] = *(const bf16x8*)(qp + 32);
        qf[3] = *(const bf16x8*)(qp + 48);
    }

    f32x16 oacc[2] = {};
    float m_run = -1e30f, l_run = 0.0f;

    int arow[2], acd[2];
#pragma unroll
    for (int i = 0; i < 2; ++i) {
        int s = w * 128 + i * 64 + lane;
        arow[i] = s >> 3;
        acd[i] = ((s & 7) ^ (arow[i] & 7)) * 8;
    }

    const int kbase = z * (SS / KVSPL);
#pragma unroll
    for (int i = 0; i < 2; ++i) {
        gload_lds16(QKV + (size_t)(b * SS + kbase + arow[i]) * 2304 + DD + h * 64 + acd[i],
                    &Ks[(w * 128 + i * 64) * 8]);
        gload_lds16(Vt + (size_t)(bh * 64 + arow[i]) * SS + kbase + acd[i],
                    &Vs[(w * 128 + i * 64) * 8]);
    }
    __syncthreads();

    int cb = 0;
    const int NT = (SS / KVSPL) / 64;
    for (int it = 0; it < NT; ++it) {
        if (it + 1 < NT) {
            const int k0n = kbase + (it + 1) * 64;
            const int nb = (cb ^ 1) * 64 * 64;
#pragma unroll
            for (int i = 0; i < 2; ++i) {
                gload_lds16(QKV + (size_t)(b * SS + k0n + arow[i]) * 2304 + DD + h * 64 + acd[i],
                            &Ks[nb + (w * 128 + i * 64) * 8]);
                gload_lds16(Vt + (size_t)(bh * 64 + arow[i]) * SS + k0n + acd[i],
                            &Vs[nb + (w * 128 + i * 64) * 8]);
            }
        }
        const unsigned short* Kc = &Ks[cb * 64 * 64];
        const unsigned short* Vc = &Vs[cb * 64 * 64];

        // S^T tiles: st[t][r] = S[kv=32t+(r&3)+8*(r>>2)+4*hi][q=l31]
        f32x16 st[2] = {};
#pragma unroll
        for (int t = 0; t < 2; ++t) {
#pragma unroll
            for (int ks = 0; ks < 4; ++ks) {
                int row = 32 * t + l31;
                int ch = (2 * ks + hi) ^ (row & 7);
                bf16x8 kf = *(const bf16x8*)&Kc[(row * 8 + ch) * 8];
                st[t] = __builtin_amdgcn_mfma_f32_32x32x16_bf16(kf, qf[ks], st[t], 0, 0, 0);
            }
        }

        // row max over lane's 32 values (max3-fusable tree) + cross-half
        float pmax = fmaxf(st[0][0], fmaxf(st[0][1], st[0][2]));
#pragma unroll
        for (int r = 3; r < 15; r += 2) pmax = fmaxf(pmax, fmaxf(st[0][r], st[0][r + 1]));
        pmax = fmaxf(pmax, st[0][15]);
#pragma unroll
        for (int r = 0; r < 16; r += 2) pmax = fmaxf(pmax, fmaxf(st[1][r], st[1][r + 1]));
        pmax = xhalf_max(pmax) * CLOG;

        // defer-max: rescale only when some row grew by > 8
        if (!__all(pmax <= m_run + 8.0f)) {
            float mn = fmaxf(m_run, pmax);
            float corr = exp2f(m_run - mn);
#pragma unroll
            for (int d = 0; d < 2; ++d)
#pragma unroll
                for (int r = 0; r < 16; ++r) oacc[d][r] *= corr;
            l_run *= corr;
            m_run = mn;
        }

        // p = exp2(s*CLOG - m_run); pack bf16 via cvt_pk; row-sum
        unsigned int Wn[2][4][2];
        float rs = 0.0f;
#pragma unroll
        for (int t = 0; t < 2; ++t) {
#pragma unroll
            for (int blk = 0; blk < 4; ++blk) {
                float pa = exp2f(fmaf(st[t][4 * blk + 0], CLOG, -m_run));
                float pb = exp2f(fmaf(st[t][4 * blk + 1], CLOG, -m_run));
                float pc = exp2f(fmaf(st[t][4 * blk + 2], CLOG, -m_run));
                float pd = exp2f(fmaf(st[t][4 * blk + 3], CLOG, -m_run));
                rs += (pa + pb) + (pc + pd);
                Wn[t][blk][0] = cvt_pk_bf16(pa, pb);
                Wn[t][blk][1] = cvt_pk_bf16(pc, pd);
            }
        }
        l_run += xhalf_sum(rs);

        // PV: O^T += V^T @ P^T. P^T B-fragment via pswap:
        // pswap(X,Y) -> r0 = {X.lo,Y.lo} (u[0..1] src), r1 = {X.hi,Y.hi}
#pragma unroll
        for (int t = 0; t < 2; ++t) {
#pragma unroll
            for (int ks2 = 0; ks2 < 2; ++ks2) {
                unsigned int a0, a1, b0, b1;
                pswap(Wn[t][2 * ks2][0], Wn[t][2 * ks2 + 1][0], a0, a1);
                pswap(Wn[t][2 * ks2][1], Wn[t][2 * ks2 + 1][1], b0, b1);
                union { unsigned int u[4]; bf16x8 v; } pu;
                pu.u[0] = a0; pu.u[1] = b0;
                pu.u[2] = a1; pu.u[3] = b1;
#pragma unroll
                for (int d = 0; d < 2; ++d) {
                    int row = 32 * d + l31;
                    int ch = (4 * t + 2 * ks2 + hi) ^ (row & 7);
                    bf16x8 vf = *(const bf16x8*)&Vc[(row * 8 + ch) * 8];
                    oacc[d] = __builtin_amdgcn_mfma_f32_32x32x16_bf16(vf, pu.v, oacc[d], 0, 0, 0);
                }
            }
        }
        __syncthreads();
        cb ^= 1;
    }

    // epilogue: unnormalized O (bf16, cvt_pk) + (m,l)
    unsigned short* op = Opart + (size_t)z * MTOK * DD + (size_t)(b * SS + q0 + l31) * DD + h * 64;
#pragma unroll
    for (int d = 0; d < 2; ++d) {
#pragma unroll
        for (int blk = 0; blk < 4; ++blk) {
            unsigned int w0 = cvt_pk_bf16(oacc[d][4 * blk + 0], oacc[d][4 * blk + 1]);
            unsigned int w1 = cvt_pk_bf16(oacc[d][4 * blk + 2], oacc[d][4 * blk + 3]);
            *(unsigned long long*)(op + 32 * d + 8 * blk + 4 * hi) =
                (unsigned long long)w0 | ((unsigned long long)w1 << 32);
        }
    }
    if (hi == 0) {
        size_t mi = (((size_t)z * BB * HH + bh) * SS + (q0 + l31)) * 2;
        ML[mi] = m_run;
        ML[mi + 1] = l_run;
    }
}

// ---------------------------------------------------------------------------
// Combine KVSPL kv-split partials -> Ctx bf16. One block per token row.
// ---------------------------------------------------------------------------
__global__ __launch_bounds__(256) void attn_combine(const unsigned short* __restrict__ Opart,
                                                    const float* __restrict__ ML,
                                                    unsigned short* __restrict__ Ctx) {
    const int row = blockIdx.x;
    const int tid = threadIdx.x;
    const int b = row >> 11, s = row & 2047;
    unsigned short* co = Ctx + (size_t)row * DD;
#pragma unroll
    for (int i = 0; i < 3; ++i) {
        int c = tid + i * 256;
        int h = c >> 6;
        float m[KVSPL], l[KVSPL];
        float M = -1e30f;
#pragma unroll
        for (int zz = 0; zz < KVSPL; ++zz) {
            size_t mi = (((size_t)zz * BB * HH + b * HH + h) * SS + s) * 2;
            m[zz] = ML[mi]; l[zz] = ML[mi + 1];
            M = fmaxf(M, m[zz]);
        }
        float denom = 0.0f, num = 0.0f;
#pragma unroll
        for (int zz = 0; zz < KVSPL; ++zz) {
            float wgt = exp2f(m[zz] - M);
            denom += wgt * l[zz];
            num += wgt * bf2f(Opart[(size_t)zz * MTOK * DD + (size_t)row * DD + c]);
        }
        co[c] = f2bf(num / denom);
    }
}

// ---------------------------------------------------------------------------
__global__ __launch_bounds__(256) void v_transpose(const unsigned short* __restrict__ QKV,
                                                   unsigned short* __restrict__ Vt) {
    __shared__ unsigned short t[64][66];
    const int tid = threadIdx.x;
    const int bh = blockIdx.y, b = bh / HH, h = bh % HH;
    const int s0 = blockIdx.x * 64;
    const int c = tid & 63, r0 = tid >> 6;
#pragma unroll
    for (int i = 0; i < 16; ++i) {
        int r = i * 4 + r0;
        t[r][c] = QKV[(size_t)(b * SS + s0 + r) * 2304 + 1536 + h * 64 + c];
    }
    __syncthreads();
#pragma unroll
    for (int i = 0; i < 16; ++i) {
        int r = i * 4 + r0;   // dh
        Vt[((size_t)bh * 64 + r) * SS + s0 + c] = t[c][r];
    }
}

// ---------------------------------------------------------------------------
// Merged prep: one launch does x->bf16, all 6 weight transposes, bias concat.
// Block-range dispatch (uniform per block, no divergence within a block).
// ---------------------------------------------------------------------------
__device__ __forceinline__ void wtrans_body(const float* __restrict__ W,
                                            unsigned short* __restrict__ Wt,
                                            int K, int N, int rowoff,
                                            int k0, int n0, int tid,
                                            float (*t)[33]) {
    const int c = tid & 31, r0 = tid >> 5;
#pragma unroll
    for (int i = 0; i < 4; ++i) {
        int r = i * 8 + r0;
        t[r][c] = W[(size_t)(k0 + r) * N + n0 + c];
    }
    __syncthreads();
#pragma unroll
    for (int i = 0; i < 4; ++i) {
        int r = i * 8 + r0;
        Wt[(size_t)(rowoff + n0 + r) * K + k0 + c] = f2bf(t[c][r]);
    }
}

__global__ __launch_bounds__(256) void prep_all(const float* __restrict__ x,
                                                unsigned short* __restrict__ xb,
                                                const float* __restrict__ Wq,
                                                const float* __restrict__ Wk,
                                                const float* __restrict__ Wv,
                                                const float* __restrict__ Wo,
                                                const float* __restrict__ W1,
                                                const float* __restrict__ W2,
                                                unsigned short* __restrict__ Wqkvt,
                                                unsigned short* __restrict__ Wot,
                                                unsigned short* __restrict__ W1t,
                                                unsigned short* __restrict__ W2t,
                                                const float* __restrict__ bq,
                                                const float* __restrict__ bk,
                                                const float* __restrict__ bv,
                                                float* __restrict__ bqkv) {
    __shared__ float t[32][33];
    const int bid = blockIdx.x;
    const int tid = threadIdx.x;
    if (bid < 3072) {                       // x -> xb (bf16), 4 f32/thread
        int i = bid * 256 + tid;            // i < 786432
        float4 v = ((const float4*)x)[i];
        unsigned long long pk = (unsigned long long)f2bf(v.x)
                              | ((unsigned long long)f2bf(v.y) << 16)
                              | ((unsigned long long)f2bf(v.z) << 32)
                              | ((unsigned long long)f2bf(v.w) << 48);
        ((unsigned long long*)xb)[i] = pk;
    } else if (bid < 3648) {                // Wq (24x24)
        int lb = bid - 3072;
        wtrans_body(Wq, Wqkvt, DD, DD, 0, (lb % 24) * 32, (lb / 24) * 32, tid, t);
    } else if (bid < 4224) {                // Wk
        int lb = bid - 3648;
        wtrans_body(Wk, Wqkvt, DD, DD, DD, (lb % 24) * 32, (lb / 24) * 32, tid, t);
    } else if (bid < 4800) {                // Wv
        int lb = bid - 4224;
        wtrans_body(Wv, Wqkvt, DD, DD, 2 * DD, (lb % 24) * 32, (lb / 24) * 32, tid, t);
    } else if (bid < 5376) {                // Wo
        int lb = bid - 4800;
        wtrans_body(Wo, Wot, DD, DD, 0, (lb % 24) * 32, (lb / 24) * 32, tid, t);
    } else if (bid < 7680) {                // W1 (24x96): K=768, N=3072
        int lb = bid - 5376;
        wtrans_body(W1, W1t, DD, DFFN, 0, (lb % 24) * 32, (lb / 24) * 32, tid, t);
    } else if (bid < 9984) {                // W2 (96x24): K=3072, N=768
        int lb = bid - 7680;
        wtrans_body(W2, W2t, DFFN, DD, 0, (lb % 96) * 32, (lb / 96) * 32, tid, t);
    } else {                                // bias concat (3 blocks)
        int i = (bid - 9984) * 256 + tid;
        if (i < DD) { bqkv[i] = bq[i]; bqkv[DD + i] = bk[i]; bqkv[2 * DD + i] = bv[i]; }
    }
}

// ---------------------------------------------------------------------------
// out_f = LayerNorm(a + p1 + p2 [+ p3] + bias)*g + be ; WB=1 -> bf16 copy too
// ---------------------------------------------------------------------------
template <int WB, int NP>
__global__ __launch_bounds__(256) void add_ln(const float* __restrict__ a,
                                              const float* __restrict__ p1,
                                              const float* __restrict__ p2,
                                              const float* __restrict__ p3,
                                              const float* __restrict__ bias,
                                              const float* __restrict__ g,
                                              const float* __restrict__ be,
                                              float* __restrict__ outf,
                                              unsigned short* __restrict__ outb) {
    const int row = blockIdx.x;
    const int tid = threadIdx.x;
    float x[3];
    float s = 0.0f, s2 = 0.0f;
#pragma unroll
    for (int i = 0; i < 3; ++i) {
        int c = tid + i * 256;
        size_t idx = (size_t)row * DD + c;
        float v = a[idx] + p1[idx] + p2[idx] + bias[c];
        if (NP == 3) v += p3[idx];
        x[i] = v; s += v; s2 += v * v;
    }
#pragma unroll
    for (int off = 32; off; off >>= 1) {
        s += __shfl_down(s, off);
        s2 += __shfl_down(s2, off);
    }
    __shared__ float ws[8];
    const int wid = tid >> 6, lane = tid & 63;
    if (lane == 0) { ws[wid] = s; ws[4 + wid] = s2; }
    __syncthreads();
    if (tid == 0) {
        ws[0] = ws[0] + ws[1] + ws[2] + ws[3];
        ws[4] = ws[4] + ws[5] + ws[6] + ws[7];
    }
    __syncthreads();
    const float mean = ws[0] * (1.0f / DD);
    const float var = ws[4] * (1.0f / DD) - mean * mean;
    const float inv = rsqrtf(var + 1e-5f);
#pragma unroll
    for (int i = 0; i < 3; ++i) {
        int c = tid + i * 256;
        float res = (x[i] - mean) * inv * g[c] + be[c];
        outf[(size_t)row * DD + c] = res;
        if (WB) outb[(size_t)row * DD + c] = f2bf(res);
    }
}

// ---------------------------------------------------------------------------
extern "C" void kernel_launch(void* const* d_in, const int* in_sizes, int n_in,
                              void* d_out, int out_size, void* d_ws, size_t ws_size,
                              hipStream_t stream) {
    const float* x   = (const float*)d_in[0];
    const float* Wq  = (const float*)d_in[1];
    const float* bq  = (const float*)d_in[2];
    const float* Wk  = (const float*)d_in[3];
    const float* bk  = (const float*)d_in[4];
    const float* Wv  = (const float*)d_in[5];
    const float* bv  = (const float*)d_in[6];
    const float* Wo  = (const float*)d_in[7];
    const float* bo  = (const float*)d_in[8];
    const float* W1  = (const float*)d_in[9];
    const float* b1  = (const float*)d_in[10];
    const float* W2  = (const float*)d_in[11];
    const float* b2  = (const float*)d_in[12];
    const float* g1  = (const float*)d_in[13];
    const float* be1 = (const float*)d_in[14];
    const float* g2  = (const float*)d_in[15];
    const float* be2 = (const float*)d_in[16];
    float* out = (float*)d_out;

    char* w8 = (char*)d_ws;
    unsigned short* QKV = (unsigned short*)w8;                      // 18874368 B
    unsigned short* Hff = (unsigned short*)w8;                      // overlays after LN1
    unsigned short* Vt  = (unsigned short*)(w8 + 18874368);         // 6291456
    unsigned short* Ctxb  = (unsigned short*)(w8 + 25165824);       // 6291456
    unsigned short* xb    = (unsigned short*)(w8 + 31457280);       // 6291456 (also X2b)
    float* Pc   = (float*)(w8 + 25165824);                          // 12582912 (Ctxb+xb region; FFN2 3rd partial — Ctxb/X2b dead by then)
    unsigned short* Wqkvt = (unsigned short*)(w8 + 37748736);       // 3538944
    unsigned short* Wot   = (unsigned short*)(w8 + 41287680);       // 1179648
    unsigned short* W1t   = (unsigned short*)(w8 + 42467328);       // 4718592
    unsigned short* W2t   = (unsigned short*)(w8 + 47185920);       // 4718592
    float* bqkv = (float*)(w8 + 51904512);                          // 9216 (+pad)
    unsigned short* Ob = (unsigned short*)(w8 + 51916800);          // KVSPL*6291456 = 25165824
    float* Pa   = (float*)(w8 + 51916800);                          // 12582912 (GEMM partial z=0)
    float* Pb   = (float*)(w8 + 64499712);                          // 12582912 (GEMM partial z=1)
    float* X2   = (float*)(w8 + 77082624);                          // 12582912
    float* ML   = (float*)(w8 + 89665536);                          // KVSPL*393216 = 1572864

    dim3 blk(256);

    // merged prep: x->bf16, 6 weight transposes, bias concat (ONE launch)
    prep_all<<<dim3(9987), blk, 0, stream>>>(x, xb, Wq, Wk, Wv, Wo, W1, W2,
                                             Wqkvt, Wot, W1t, W2t, bq, bk, bv, bqkv);

    // fused QKV projection -> QKV bf16 [4096][2304]
    gemm_mfma<0, 1><<<dim3(32, 18, 1), blk, 0, stream>>>(xb, Wqkvt, bqkv, QKV, nullptr, nullptr,
                                                         MTOK, 3 * DD, DD, DD, DD);
    // V transpose -> Vt [24][64][2048]
    v_transpose<<<dim3(32, 24), blk, 0, stream>>>(QKV, Vt);
    // attention, kv-split=4 -> Ob (unnormalized bf16) + ML
    attn_mfma5<<<dim3(SS / 128, BB * HH, KVSPL), blk, 0, stream>>>(QKV, Vt, Ob, ML);
    // combine -> Ctxb bf16
    attn_combine<<<dim3(MTOK), blk, 0, stream>>>(Ob, ML, Ctxb);
    // output projection, split-K=2 in ONE launch -> Pa/Pb
    gemm_mfma<0, 0><<<dim3(32, 6, 2), blk, 0, stream>>>(Ctxb, Wot, nullptr, Pa, Pb, Pb,
                                                        MTOK, DD, DD, DD, 384);
    // residual + Wo-partials + bias + LN1 -> X2 fp32 + X2b bf16 (xb region)
    add_ln<1, 2><<<dim3(MTOK), blk, 0, stream>>>(x, Pa, Pb, Pa, bo, g1, be1, X2, xb);
    // FFN1 + GELU -> Hff bf16
    gemm_mfma<1, 1><<<dim3(32, 24, 1), blk, 0, stream>>>(xb, W1t, b1, Hff, nullptr, nullptr,
                                                         MTOK, DFFN, DD, DD, DD);
    // FFN2, split-K=3 in ONE launch -> Pa/Pb/Pc (Ctxb+X2b region now dead)
    gemm_mfma<0, 0><<<dim3(32, 6, 3), blk, 0, stream>>>(Hff, W2t, nullptr, Pa, Pb, Pc,
                                                        MTOK, DD, DFFN, DFFN, 1024);
    // residual + FFN2-partials + bias + LN2 -> out
    add_ln<0, 3><<<dim3(MTOK), blk, 0, stream>>>(X2, Pa, Pb, Pc, b2, g2, be2, out, nullptr);
}